// Round 17
// baseline (238.519 us; speedup 1.0000x reference)
//
#include <hip/hip_runtime.h>
#include <stdint.h>

#define FD    512
#define SEQ   2048
#define NHALF 8192
#define NTOT  16384
#define QKVN  1536

typedef unsigned short u16;
typedef __attribute__((ext_vector_type(8))) short short8;
typedef __attribute__((ext_vector_type(4))) float f32x4;

__device__ __forceinline__ u16 f2bf(float f){
  union { float f; uint32_t i; } v; v.f = f;
  uint32_t r = v.i + 0x7FFFu + ((v.i >> 16) & 1u);
  return (u16)(r >> 16);
}

__device__ __forceinline__ void gload_lds16(const void* g, void* l){
  __builtin_amdgcn_global_load_lds((const __attribute__((address_space(1))) void*)g,
                                   (__attribute__((address_space(3))) void*)l, 16, 0, 0);
}

__device__ __forceinline__ f32x4 mfma16(short8 a, short8 b, f32x4 c){
  return __builtin_amdgcn_mfma_f32_16x16x32_bf16(a, b, c, 0, 0, 0);
}

__device__ __forceinline__ uint32_t cvtpk(float lo, float hi){
  uint32_t r; asm("v_cvt_pk_bf16_f32 %0, %1, %2" : "=v"(r) : "v"(lo), "v"(hi)); return r;
}

// single-instruction 2^x (v_exp_f32); exp2f() without fast-math is a slow OCML poly
__device__ __forceinline__ float fexp2(float x){
  float r; asm("v_exp_f32 %0, %1" : "=v"(r) : "v"(x)); return r;
}

// ---- weight convert + transpose via LDS tile: wt[mat][n][k] = bf16(w[k][n]) ----
__global__ __launch_bounds__(256) void wconv_kernel(
    const float* __restrict__ w0, const float* __restrict__ w1,
    const float* __restrict__ w2, const float* __restrict__ w3,
    const float* __restrict__ w4, const float* __restrict__ w5,
    const float* __restrict__ w6, const float* __restrict__ w7,
    u16* __restrict__ out)
{
  int mat = blockIdx.x >> 6;
  const float* w = w0;
  switch (mat){ case 1: w=w1; break; case 2: w=w2; break; case 3: w=w3; break;
                case 4: w=w4; break; case 5: w=w5; break; case 6: w=w6; break;
                case 7: w=w7; break; default: break; }
  int tile = blockIdx.x & 63;
  int k0 = (tile >> 3) << 6, n0 = (tile & 7) << 6;

  __shared__ float lt[64][65];
  int tid = threadIdx.x;
  int tr = tid >> 4, tc = (tid & 15) << 2;
  #pragma unroll
  for (int p = 0; p < 4; p++){
    int k = p * 16 + tr;
    float4 v = *(const float4*)&w[(size_t)(k0 + k) * 512 + n0 + tc];
    lt[k][tc] = v.x; lt[k][tc + 1] = v.y; lt[k][tc + 2] = v.z; lt[k][tc + 3] = v.w;
  }
  __syncthreads();
  int n = tid >> 2, kc = (tid & 3) << 4;
  u16 buf[16];
  #pragma unroll
  for (int j = 0; j < 16; j++) buf[j] = f2bf(lt[kc + j][n]);
  u16* dst = out + ((size_t)mat << 18) + (size_t)(n0 + n) * 512 + k0 + kc;
  *(short8*)dst       = *(const short8*)(buf);
  *(short8*)(dst + 8) = *(const short8*)(buf + 8);
}

__global__ __launch_bounds__(256) void biascat_kernel(
    const float* __restrict__ bq, const float* __restrict__ bk,
    const float* __restrict__ bv, float* __restrict__ o)
{
  int i = blockIdx.x * 256 + threadIdx.x;      // grid 6 -> 0..1535
  if (i < 512) o[i] = bq[i];
  else if (i < 1024) o[i] = bk[i - 512];
  else o[i] = bv[i - 1024];
}

// ---- layernorm over F=512, two halves with separate params, bf16 out ----
__global__ __launch_bounds__(256) void ln_kernel(
    const float* __restrict__ xa, const float* __restrict__ xb,
    const float* __restrict__ ga, const float* __restrict__ ba,
    const float* __restrict__ gb, const float* __restrict__ bb,
    u16* __restrict__ out)
{
  int row = blockIdx.x;
  const float* x; const float* g; const float* bi;
  if (row < NHALF){ x = xa + (size_t)row * FD; g = ga; bi = ba; }
  else            { x = xb + (size_t)(row - NHALF) * FD; g = gb; bi = bb; }
  int t = threadIdx.x;
  float2 v = ((const float2*)x)[t];
  __shared__ float red[8];
  float s = v.x + v.y;
  #pragma unroll
  for (int o = 32; o; o >>= 1) s += __shfl_xor(s, o, 64);
  if ((t & 63) == 0) red[t >> 6] = s;
  __syncthreads();
  float mu = (red[0] + red[1] + red[2] + red[3]) * (1.0f / 512.0f);
  float d0 = v.x - mu, d1 = v.y - mu;
  float q = d0 * d0 + d1 * d1;
  #pragma unroll
  for (int o = 32; o; o >>= 1) q += __shfl_xor(q, o, 64);
  if ((t & 63) == 0) red[4 + (t >> 6)] = q;
  __syncthreads();
  float var = (red[4] + red[5] + red[6] + red[7]) * (1.0f / 512.0f);
  float rs = rsqrtf(var + 1e-6f);
  out[(size_t)row * FD + 2 * t]     = f2bf(d0 * rs * g[2 * t]     + bi[2 * t]);
  out[(size_t)row * FD + 2 * t + 1] = f2bf(d1 * rs * g[2 * t + 1] + bi[2 * t + 1]);
}

// ---- V transpose: vt[slab][d][k] = qkv[dir*8192+b*2048+k][1024+h*64+d] ----
__global__ __launch_bounds__(256) void vtr_kernel(
    const u16* __restrict__ qkv, u16* __restrict__ vt)
{
  int kc = blockIdx.x & 15;        // k chunk of 128
  int s  = blockIdx.x >> 4;        // 0..63
  int dir = s >> 5, b = (s >> 3) & 3, h = s & 7;
  int t = threadIdx.x;
  int d = t & 63, kb = t >> 6;     // kb 0..3
  const u16* src = qkv + (size_t)(dir * NHALF + b * SEQ + kc * 128 + kb * 32) * QKVN
                       + 1024 + h * 64 + d;
  u16* dst = vt + (size_t)s * 131072 + (size_t)d * 2048 + kc * 128 + kb * 32;
  u16 buf[32];
  #pragma unroll
  for (int j = 0; j < 32; j++) buf[j] = src[(size_t)j * QKVN];
  #pragma unroll
  for (int j = 0; j < 4; j++)
    *(short8*)(dst + j * 8) = *(const short8*)(buf + j * 8);
}

// ---- GEMM: C = A[M,K] @ Bt[N,K]^T + bias (+res), 128x128 tile, BK=32 ----
// 3-deep pipeline with counted vmcnt; conflict-free [64][64] swizzled tiles.
template<bool RELU, bool OUT_BF16, bool HAS_RES>
__global__ __launch_bounds__(256) void gemm_bt(
    const u16* __restrict__ A,
    const u16* __restrict__ BtLo, const u16* __restrict__ BtHi,
    const float* __restrict__ biasLo, const float* __restrict__ biasHi,
    const float* __restrict__ resLo, const float* __restrict__ resHi,
    void* __restrict__ outp,
    int M, int N, int K, int halfM)
{
  __shared__ __align__(16) u16 lA[3][64 * 64];
  __shared__ __align__(16) u16 lB[3][64 * 64];
  int nwg = gridDim.x;
  int bid = (blockIdx.x & 7) * (nwg >> 3) + (blockIdx.x >> 3);
  int nTN = N >> 7;
  int bm = bid / nTN, bn = bid - bm * nTN;
  int rowBase = bm << 7, colBase = bn << 7;
  bool inLo = rowBase < halfM;
  const u16* Bt = inLo ? BtLo : BtHi;
  const float* bias = inLo ? biasLo : biasHi;
  const float* res = inLo ? resLo : resHi;
  int rowLocalBase = inLo ? rowBase : rowBase - halfM;

  int tid = threadIdx.x, wv = tid >> 6, ln = tid & 63;
  int g = ln >> 4, la = ln & 15;

  f32x4 acc[4][4];
  #pragma unroll
  for (int m = 0; m < 4; m++)
    #pragma unroll
    for (int n = 0; n < 4; n++) acc[m][n] = (f32x4){0.f, 0.f, 0.f, 0.f};

  int r   = tid >> 3;
  int sl  = (tid & 7) ^ (r & 7);
  int shalf = sl >> 2, sk8 = (sl & 3) << 3;
  const u16* gA0 = A  + (size_t)(rowBase + r + shalf * 64) * K + sk8;
  const u16* gB0 = Bt + (size_t)(colBase + r + shalf * 64) * K + sk8;
  const size_t row32 = (size_t)32 * K;

  int caA = (((wv >> 1) << 5) + (g << 3)) ^ ((la & 7) << 3);
  int caB = (((wv & 1) << 5) + (g << 3)) ^ ((la & 7) << 3);

  int arow = (wv >> 1) << 6, bcol = (wv & 1) << 6;

  #define STAGE(buf, kt) do { \
    gload_lds16(gA0 + (kt), (char*)lA[buf] + wv * 1024); \
    gload_lds16(gA0 + (kt) + row32, (char*)lA[buf] + 4096 + wv * 1024); \
    gload_lds16(gB0 + (kt), (char*)lB[buf] + wv * 1024); \
    gload_lds16(gB0 + (kt) + row32, (char*)lB[buf] + 4096 + wv * 1024); } while (0)

  int nK = K >> 5;
  STAGE(0, 0);
  STAGE(1, 32);

  for (int i = 0; i < nK; i++){
    if (i < nK - 1) asm volatile("s_waitcnt vmcnt(4)" ::: "memory");
    else            asm volatile("s_waitcnt vmcnt(0)" ::: "memory");
    __builtin_amdgcn_s_barrier();
    __builtin_amdgcn_sched_barrier(0);
    int cur = i % 3;
    if (i + 2 < nK) STAGE((i + 2) % 3, (i + 2) << 5);
    short8 af[4], bfr[4];
    #pragma unroll
    for (int m = 0; m < 4; m++)
      af[m] = *(const short8*)&lA[cur][((m << 4) + la) * 64 + caA];
    #pragma unroll
    for (int n = 0; n < 4; n++)
      bfr[n] = *(const short8*)&lB[cur][((n << 4) + la) * 64 + caB];
    #pragma unroll
    for (int m = 0; m < 4; m++)
      #pragma unroll
      for (int n = 0; n < 4; n++)
        acc[m][n] = mfma16(af[m], bfr[n], acc[m][n]);
  }
  #undef STAGE

  #pragma unroll
  for (int n = 0; n < 4; n++){
    int col = colBase + bcol + (n << 4) + la;
    float bv = bias[col];
    #pragma unroll
    for (int m = 0; m < 4; m++){
      int rowT = arow + (m << 4) + (g << 2);
      #pragma unroll
      for (int rr = 0; rr < 4; rr++){
        float v = acc[m][n][rr] + bv;
        if (RELU) v = fmaxf(v, 0.f);
        if (HAS_RES) v += res[(size_t)(rowLocalBase + rowT + rr) * N + col];
        if (OUT_BF16) ((u16*)outp)[(size_t)(rowBase + rowT + rr) * N + col] = f2bf(v);
        else ((float*)outp)[(size_t)(rowBase + rowT + rr) * N + col] = v;
      }
    }
  }
}

// ---- flash cross-attention: 8 waves x 64 q-rows (4 rgroups), Q=512/block ----
// K/V frags read ONCE per wave per tile, feed 4 rgroups (halves per-q LDS
// traffic vs R13). Per key-half: QK^T(2 key-blocks) -> P -> PV, P in per-wave
// [32][64] buffer (rg-pairs in column halves, R13-proven swizzle). Q frags via
// 8 one-time global loads. Grid 256 = 1 block/CU, LDS 64KB.
__global__ __launch_bounds__(512) void attn_kernel(
    const u16* __restrict__ qkv, const u16* __restrict__ vt, u16* __restrict__ fb)
{
  // XCD-chunked swizzle: 4 qt-blocks sharing a K/V slab stay on one XCD
  int l = (blockIdx.x & 7) * 32 + (blockIdx.x >> 3);
  int qt = l & 3;                 // 0..3
  int h  = (l >> 2) & 7;          // 0..7
  int z  = l >> 5;                // dir*4 + b
  int dir = z >> 2, b = z & 3;
  int qRow0  = dir * NHALF + b * SEQ + qt * 512;
  int kvRow0 = (dir ^ 1) * NHALF + b * SEQ;
  int colQ = h * 64;

  __shared__ __align__(16) u16 lK[2][64 * 64];
  __shared__ __align__(16) u16 lVt[2][64 * 64];
  __shared__ __align__(16) u16 lP[8][32 * 64];

  int tid = threadIdx.x, wv = tid >> 6, ln = tid & 63;
  int g = ln >> 4, lo = ln & 15;

  int srow = tid >> 3;                         // 0..63
  int soff = ((tid & 7) ^ (srow & 7)) * 8;

  const float CEXP = 0.18033688f;   // 0.125 * log2(e)

  int ca0 = (g * 8) ^ ((lo & 7) << 3);
  int ca1 = (32 + g * 8) ^ ((lo & 7) << 3);
  int lo64 = lo * 64;

  // P buffer [32 rows][64 u16]/wave: row=(rg&1)*16+lo, col-half=(rg>>1).
  int pw[4][2], pr[4];
  #pragma unroll
  for (int rg = 0; rg < 4; rg++){
    int rowp = (((rg & 1) << 4) + lo) * 64;
    #pragma unroll
    for (int nn = 0; nn < 2; nn++){
      int slot = (((rg >> 1) << 2) + (nn << 1) + (g >> 1)) ^ (lo & 7);
      pw[rg][nn] = rowp + slot * 8 + ((g & 1) << 2);
    }
    int slotr = (((rg >> 1) << 2) + g) ^ (lo & 7);
    pr[rg] = rowp + slotr * 8;
  }

  const u16* vtbase = vt + (size_t)((dir ^ 1) * 32 + b * 8 + h) * 131072;
  const u16* kp0 = qkv + (size_t)(kvRow0 + srow) * QKVN + 512 + colQ + soff;
  const u16* vp0 = vtbase + (size_t)srow * 2048 + soff;

  char* dK0 = (char*)lK[0] + wv * 1024;
  char* dV0 = (char*)lVt[0] + wv * 1024;
  const u16* lKf = &lK[0][0];
  const u16* lVf = &lVt[0][0];
  u16* lPw = &lP[wv][0];

  // ---- Q frags direct from global (B-frag rows are contiguous 16B) ----
  short8 qf[4][2];
  {
    const u16* qptr = qkv + (size_t)(qRow0 + wv * 64 + lo) * QKVN + colQ + g * 8;
    #pragma unroll
    for (int rg = 0; rg < 4; rg++){
      qf[rg][0] = *(const short8*)(qptr + (size_t)(rg * 16) * QKVN);
      qf[rg][1] = *(const short8*)(qptr + (size_t)(rg * 16) * QKVN + 32);
    }
  }

  // ---- stage K(0), Vt(0) ----
  gload_lds16(kp0, dK0);
  gload_lds16(vp0, dV0);
  kp0 += (size_t)64 * QKVN; vp0 += 64;
  __syncthreads();

  f32x4 acc_o[4][4];                // [rg][nd]
  f32x4 acc_l[4];
  float m_l[4];
  #pragma unroll
  for (int rg = 0; rg < 4; rg++){
    #pragma unroll
    for (int nd = 0; nd < 4; nd++) acc_o[rg][nd] = (f32x4){0.f, 0.f, 0.f, 0.f};
    acc_l[rg] = (f32x4){0.f, 0.f, 0.f, 0.f};
    m_l[rg] = 0.f;                  // eager-P bound: P <= 2^(max) , defer-max keeps it sane
  }
  const f32x4 z4 = (f32x4){0.f, 0.f, 0.f, 0.f};

  short8 ones;
  #pragma unroll
  for (int j = 0; j < 8; j++) ones[j] = (short)0x3F80;

  int cb = 0;
  for (int t = 0; t < 32; t++){
    if (t < 31){
      int nb = cb ^ 8192;
      gload_lds16(kp0, dK0 + nb);
      gload_lds16(vp0, dV0 + nb);
      kp0 += (size_t)64 * QKVN; vp0 += 64;
    }
    const u16* lk = (const u16*)((const char*)lKf + cb);
    const u16* lv = (const u16*)((const char*)lVf + cb);

    float m0[4] = {-1e30f, -1e30f, -1e30f, -1e30f};

    #pragma unroll
    for (int kh = 0; kh < 2; kh++){
      // QK^T for this key-half: K frags read once, feed 4 rgroups
      #pragma unroll
      for (int nn = 0; nn < 2; nn++){
        int n = kh * 2 + nn;
        short8 kfa = *(const short8*)&lk[lo64 + n * 1024 + ca0];
        short8 kfb = *(const short8*)&lk[lo64 + n * 1024 + ca1];
        f32x4 s_[4];
        #pragma unroll
        for (int rg = 0; rg < 4; rg++){
          s_[rg] = mfma16(kfa, qf[rg][0], z4);
          s_[rg] = mfma16(kfb, qf[rg][1], s_[rg]);
        }
        #pragma unroll
        for (int rg = 0; rg < 4; rg++){
          float a = fmaxf(fmaxf(s_[rg][0], s_[rg][1]), fmaxf(s_[rg][2], s_[rg][3]));
          m0[rg] = fmaxf(m0[rg], a);
          float p0 = fexp2(fmaf(s_[rg][0], CEXP, -m_l[rg]));
          float p1 = fexp2(fmaf(s_[rg][1], CEXP, -m_l[rg]));
          float p2 = fexp2(fmaf(s_[rg][2], CEXP, -m_l[rg]));
          float p3 = fexp2(fmaf(s_[rg][3], CEXP, -m_l[rg]));
          uint2 w; w.x = cvtpk(p0, p1); w.y = cvtpk(p2, p3);
          *(uint2*)&lPw[pw[rg][nn]] = w;
        }
      }
      // PV for this key-half (same-wave DS ordering: P reads precede half1 writes)
      short8 pf[4];
      #pragma unroll
      for (int rg = 0; rg < 4; rg++){
        pf[rg] = *(const short8*)&lPw[pr[rg]];
        acc_l[rg] = mfma16(pf[rg], ones, acc_l[rg]);
      }
      int cav = kh ? ca1 : ca0;
      #pragma unroll
      for (int nd = 0; nd < 4; nd++){
        short8 vf = *(const short8*)&lv[lo64 + nd * 1024 + cav];
        #pragma unroll
        for (int rg = 0; rg < 4; rg++)
          acc_o[rg][nd] = mfma16(pf[rg], vf, acc_o[rg][nd]);
      }
    }

    // defer-max: finish cross-g max, rescale only if some row grew > 8 (log2)
    bool ok = true;
    #pragma unroll
    for (int rg = 0; rg < 4; rg++){
      m0[rg] = fmaxf(m0[rg], __shfl_xor(m0[rg], 16, 64));
      m0[rg] = fmaxf(m0[rg], __shfl_xor(m0[rg], 32, 64));
      m0[rg] *= CEXP;
      ok = ok && (m0[rg] <= m_l[rg] + 8.f);
    }
    if (!__all(ok)){
      #pragma unroll
      for (int rg = 0; rg < 4; rg++){
        float mn = fmaxf(m_l[rg], m0[rg]);
        float a0 = fexp2(m_l[rg] - mn);
        m_l[rg] = mn;
        #pragma unroll
        for (int rr = 0; rr < 4; rr++){
          float ar = __shfl(a0, g * 4 + rr, 64);
          acc_l[rg][rr] *= ar;
          #pragma unroll
          for (int nd = 0; nd < 4; nd++) acc_o[rg][nd][rr] *= ar;
        }
      }
    }

    cb ^= 8192;
    __syncthreads();
  }

  #pragma unroll
  for (int rg = 0; rg < 4; rg++){
    #pragma unroll
    for (int rr = 0; rr < 4; rr++){
      float rl = 1.0f / acc_l[rg][rr];
      #pragma unroll
      for (int nd = 0; nd < 4; nd++){
        int row = qRow0 + wv * 64 + rg * 16 + g * 4 + rr;
        int d   = colQ + (nd << 4) + lo;
        fb[(size_t)row * FD + d] = f2bf(acc_o[rg][nd][rr] * rl);
      }
    }
  }
}

extern "C" void kernel_launch(void* const* d_in, const int* in_sizes, int n_in,
                              void* d_out, int out_size, void* d_ws, size_t ws_size,
                              hipStream_t stream)
{
  const float* t1   = (const float*)d_in[0];
  const float* t2   = (const float*)d_in[1];
  const float* ln1g = (const float*)d_in[2];
  const float* ln1b = (const float*)d_in[3];
  const float* ln2g = (const float*)d_in[4];
  const float* ln2b = (const float*)d_in[5];
  const float* Wq   = (const float*)d_in[6];
  const float* bq   = (const float*)d_in[7];
  const float* Wk   = (const float*)d_in[8];
  const float* bk   = (const float*)d_in[9];
  const float* Wv   = (const float*)d_in[10];
  const float* bv   = (const float*)d_in[11];
  const float* Wfc  = (const float*)d_in[12];
  const float* bfc  = (const float*)d_in[13];
  const float* f1lg = (const float*)d_in[14];
  const float* f1lb = (const float*)d_in[15];
  const float* W11  = (const float*)d_in[16];
  const float* b11  = (const float*)d_in[17];
  const float* W12  = (const float*)d_in[18];
  const float* b12  = (const float*)d_in[19];
  const float* f2lg = (const float*)d_in[20];
  const float* f2lb = (const float*)d_in[21];
  const float* W21  = (const float*)d_in[22];
  const float* b21  = (const float*)d_in[23];
  const float* W22  = (const float*)d_in[24];
  const float* b22  = (const float*)d_in[25];

  char* ws = (char*)d_ws;
  const size_t MB = 1024 * 1024;
  u16* wt     = (u16*)ws;                  // 8 x [512,512] bf16 (transposed)
  u16* tln    = (u16*)(ws + 4 * MB);       // [16384,512]   (dead after QKV GEMM)
  u16* qkv    = (u16*)(ws + 20 * MB);      // [16384,1536]
  u16* fb     = (u16*)(ws + 68 * MB);      // [16384,512]
  float* bqkv = (float*)(ws + 84 * MB);    // [1536]
  u16* vtb    = tln;                       // 16 MB, reuses tln (lifetime-disjoint)
  u16* xln    = tln;                       // reuse after attn
  u16* hb     = qkv;                       // reuse
  float* out  = (float*)d_out;

  wconv_kernel<<<512, 256, 0, stream>>>(Wq, Wk, Wv, Wfc, W11, W12, W21, W22, wt);
  biascat_kernel<<<6, 256, 0, stream>>>(bq, bk, bv, bqkv);
  ln_kernel<<<NTOT, 256, 0, stream>>>(t1, t2, ln1g, ln1b, ln2g, ln2b, tln);
  gemm_bt<false, true, false><<<1536, 256, 0, stream>>>(
      tln, wt, wt, bqkv, bqkv, nullptr, nullptr, qkv, NTOT, QKVN, FD, NTOT);
  vtr_kernel<<<1024, 256, 0, stream>>>(qkv, vtb);
  attn_kernel<<<256, 512, 0, stream>>>(qkv, vtb, fb);
  gemm_bt<false, false, true><<<512, 256, 0, stream>>>(
      fb, wt + 3 * 262144, wt + 3 * 262144, bfc, bfc, t1, t2, out, NTOT, FD, FD, NHALF);
  ln_kernel<<<NTOT, 256, 0, stream>>>(out, out + (size_t)NHALF * FD, f1lg, f1lb, f2lg, f2lb, xln);
  gemm_bt<true, true, false><<<512, 256, 0, stream>>>(
      xln, wt + 4 * 262144, wt + 6 * 262144, b11, b21, nullptr, nullptr, hb, NTOT, FD, FD, NHALF);
  gemm_bt<false, false, true><<<512, 256, 0, stream>>>(
      hb, wt + 5 * 262144, wt + 7 * 262144, b12, b22, out, out + (size_t)NHALF * FD, out, NTOT, FD, FD, NHALF);
}

// Round 18
// 224.313 us; speedup vs baseline: 1.0633x; 1.0633x over previous
//
#include <hip/hip_runtime.h>
#include <stdint.h>

#define FD    512
#define SEQ   2048
#define NHALF 8192
#define NTOT  16384
#define QKVN  1536

typedef unsigned short u16;
typedef __attribute__((ext_vector_type(8))) short short8;
typedef __attribute__((ext_vector_type(4))) float f32x4;

__device__ __forceinline__ u16 f2bf(float f){
  union { float f; uint32_t i; } v; v.f = f;
  uint32_t r = v.i + 0x7FFFu + ((v.i >> 16) & 1u);
  return (u16)(r >> 16);
}

__device__ __forceinline__ void gload_lds16(const void* g, void* l){
  __builtin_amdgcn_global_load_lds((const __attribute__((address_space(1))) void*)g,
                                   (__attribute__((address_space(3))) void*)l, 16, 0, 0);
}

__device__ __forceinline__ f32x4 mfma16(short8 a, short8 b, f32x4 c){
  return __builtin_amdgcn_mfma_f32_16x16x32_bf16(a, b, c, 0, 0, 0);
}

__device__ __forceinline__ uint32_t cvtpk(float lo, float hi){
  uint32_t r; asm("v_cvt_pk_bf16_f32 %0, %1, %2" : "=v"(r) : "v"(lo), "v"(hi)); return r;
}

// single-instruction 2^x (v_exp_f32); exp2f() without fast-math is a slow OCML poly
__device__ __forceinline__ float fexp2(float x){
  float r; asm("v_exp_f32 %0, %1" : "=v"(r) : "v"(x)); return r;
}

// ---- weight convert + transpose via LDS tile: wt[mat][n][k] = bf16(w[k][n]) ----
__global__ __launch_bounds__(256) void wconv_kernel(
    const float* __restrict__ w0, const float* __restrict__ w1,
    const float* __restrict__ w2, const float* __restrict__ w3,
    const float* __restrict__ w4, const float* __restrict__ w5,
    const float* __restrict__ w6, const float* __restrict__ w7,
    u16* __restrict__ out)
{
  int mat = blockIdx.x >> 6;
  const float* w = w0;
  switch (mat){ case 1: w=w1; break; case 2: w=w2; break; case 3: w=w3; break;
                case 4: w=w4; break; case 5: w=w5; break; case 6: w=w6; break;
                case 7: w=w7; break; default: break; }
  int tile = blockIdx.x & 63;
  int k0 = (tile >> 3) << 6, n0 = (tile & 7) << 6;

  __shared__ float lt[64][65];
  int tid = threadIdx.x;
  int tr = tid >> 4, tc = (tid & 15) << 2;
  #pragma unroll
  for (int p = 0; p < 4; p++){
    int k = p * 16 + tr;
    float4 v = *(const float4*)&w[(size_t)(k0 + k) * 512 + n0 + tc];
    lt[k][tc] = v.x; lt[k][tc + 1] = v.y; lt[k][tc + 2] = v.z; lt[k][tc + 3] = v.w;
  }
  __syncthreads();
  int n = tid >> 2, kc = (tid & 3) << 4;
  u16 buf[16];
  #pragma unroll
  for (int j = 0; j < 16; j++) buf[j] = f2bf(lt[kc + j][n]);
  u16* dst = out + ((size_t)mat << 18) + (size_t)(n0 + n) * 512 + k0 + kc;
  *(short8*)dst       = *(const short8*)(buf);
  *(short8*)(dst + 8) = *(const short8*)(buf + 8);
}

__global__ __launch_bounds__(256) void biascat_kernel(
    const float* __restrict__ bq, const float* __restrict__ bk,
    const float* __restrict__ bv, float* __restrict__ o)
{
  int i = blockIdx.x * 256 + threadIdx.x;      // grid 6 -> 0..1535
  if (i < 512) o[i] = bq[i];
  else if (i < 1024) o[i] = bk[i - 512];
  else o[i] = bv[i - 1024];
}

// ---- layernorm, wave-per-row: 4 rows/block, no LDS, no barriers ----
// lane owns 8 contiguous floats (2x float4), 6x shfl_xor full-wave reduce.
__global__ __launch_bounds__(256) void ln_kernel(
    const float* __restrict__ xa, const float* __restrict__ xb,
    const float* __restrict__ ga, const float* __restrict__ ba,
    const float* __restrict__ gb, const float* __restrict__ bb,
    u16* __restrict__ out)
{
  int row = (blockIdx.x << 2) + (threadIdx.x >> 6);
  int ln = threadIdx.x & 63;
  const float* x; const float* g; const float* bi;
  if (row < NHALF){ x = xa + (size_t)row * FD; g = ga; bi = ba; }
  else            { x = xb + (size_t)(row - NHALF) * FD; g = gb; bi = bb; }
  int c = ln << 3;
  float4 v0 = *(const float4*)&x[c];
  float4 v1 = *(const float4*)&x[c + 4];
  float d[8] = {v0.x, v0.y, v0.z, v0.w, v1.x, v1.y, v1.z, v1.w};
  float s = (d[0] + d[1]) + (d[2] + d[3]) + (d[4] + d[5]) + (d[6] + d[7]);
  #pragma unroll
  for (int o = 32; o; o >>= 1) s += __shfl_xor(s, o, 64);
  float mu = s * (1.0f / 512.0f);
  float q = 0.f;
  #pragma unroll
  for (int j = 0; j < 8; j++){ d[j] -= mu; q += d[j] * d[j]; }
  #pragma unroll
  for (int o = 32; o; o >>= 1) q += __shfl_xor(q, o, 64);
  float rs = rsqrtf(q * (1.0f / 512.0f) + 1e-6f);
  float4 g0 = *(const float4*)&g[c],  g1 = *(const float4*)&g[c + 4];
  float4 b0 = *(const float4*)&bi[c], b1 = *(const float4*)&bi[c + 4];
  float gg[8] = {g0.x, g0.y, g0.z, g0.w, g1.x, g1.y, g1.z, g1.w};
  float bbv[8] = {b0.x, b0.y, b0.z, b0.w, b1.x, b1.y, b1.z, b1.w};
  u16 o8[8];
  #pragma unroll
  for (int j = 0; j < 8; j++) o8[j] = f2bf(d[j] * rs * gg[j] + bbv[j]);
  *(short8*)&out[(size_t)row * FD + c] = *(const short8*)o8;
}

// ---- V transpose: vt[slab][d][k] = qkv[dir*8192+b*2048+k][1024+h*64+d] ----
__global__ __launch_bounds__(256) void vtr_kernel(
    const u16* __restrict__ qkv, u16* __restrict__ vt)
{
  int kc = blockIdx.x & 15;        // k chunk of 128
  int s  = blockIdx.x >> 4;        // 0..63
  int dir = s >> 5, b = (s >> 3) & 3, h = s & 7;
  int t = threadIdx.x;
  int d = t & 63, kb = t >> 6;     // kb 0..3
  const u16* src = qkv + (size_t)(dir * NHALF + b * SEQ + kc * 128 + kb * 32) * QKVN
                       + 1024 + h * 64 + d;
  u16* dst = vt + (size_t)s * 131072 + (size_t)d * 2048 + kc * 128 + kb * 32;
  u16 buf[32];
  #pragma unroll
  for (int j = 0; j < 32; j++) buf[j] = src[(size_t)j * QKVN];
  #pragma unroll
  for (int j = 0; j < 4; j++)
    *(short8*)(dst + j * 8) = *(const short8*)(buf + j * 8);
}

// ---- GEMM: C = A[M,K] @ Bt[N,K]^T + bias (+res), 128x128 tile, BK=32 ----
// 3-deep pipeline with counted vmcnt; conflict-free [64][64] swizzled tiles.
template<bool RELU, bool OUT_BF16, bool HAS_RES>
__global__ __launch_bounds__(256) void gemm_bt(
    const u16* __restrict__ A,
    const u16* __restrict__ BtLo, const u16* __restrict__ BtHi,
    const float* __restrict__ biasLo, const float* __restrict__ biasHi,
    const float* __restrict__ resLo, const float* __restrict__ resHi,
    void* __restrict__ outp,
    int M, int N, int K, int halfM)
{
  __shared__ __align__(16) u16 lA[3][64 * 64];
  __shared__ __align__(16) u16 lB[3][64 * 64];
  int nwg = gridDim.x;
  int bid = (blockIdx.x & 7) * (nwg >> 3) + (blockIdx.x >> 3);
  int nTN = N >> 7;
  int bm = bid / nTN, bn = bid - bm * nTN;
  int rowBase = bm << 7, colBase = bn << 7;
  bool inLo = rowBase < halfM;
  const u16* Bt = inLo ? BtLo : BtHi;
  const float* bias = inLo ? biasLo : biasHi;
  const float* res = inLo ? resLo : resHi;
  int rowLocalBase = inLo ? rowBase : rowBase - halfM;

  int tid = threadIdx.x, wv = tid >> 6, ln = tid & 63;
  int g = ln >> 4, la = ln & 15;

  f32x4 acc[4][4];
  #pragma unroll
  for (int m = 0; m < 4; m++)
    #pragma unroll
    for (int n = 0; n < 4; n++) acc[m][n] = (f32x4){0.f, 0.f, 0.f, 0.f};

  int r   = tid >> 3;
  int sl  = (tid & 7) ^ (r & 7);
  int shalf = sl >> 2, sk8 = (sl & 3) << 3;
  const u16* gA0 = A  + (size_t)(rowBase + r + shalf * 64) * K + sk8;
  const u16* gB0 = Bt + (size_t)(colBase + r + shalf * 64) * K + sk8;
  const size_t row32 = (size_t)32 * K;

  int caA = (((wv >> 1) << 5) + (g << 3)) ^ ((la & 7) << 3);
  int caB = (((wv & 1) << 5) + (g << 3)) ^ ((la & 7) << 3);

  int arow = (wv >> 1) << 6, bcol = (wv & 1) << 6;

  #define STAGE(buf, kt) do { \
    gload_lds16(gA0 + (kt), (char*)lA[buf] + wv * 1024); \
    gload_lds16(gA0 + (kt) + row32, (char*)lA[buf] + 4096 + wv * 1024); \
    gload_lds16(gB0 + (kt), (char*)lB[buf] + wv * 1024); \
    gload_lds16(gB0 + (kt) + row32, (char*)lB[buf] + 4096 + wv * 1024); } while (0)

  int nK = K >> 5;
  STAGE(0, 0);
  STAGE(1, 32);

  for (int i = 0; i < nK; i++){
    if (i < nK - 1) asm volatile("s_waitcnt vmcnt(4)" ::: "memory");
    else            asm volatile("s_waitcnt vmcnt(0)" ::: "memory");
    __builtin_amdgcn_s_barrier();
    __builtin_amdgcn_sched_barrier(0);
    int cur = i % 3;
    if (i + 2 < nK) STAGE((i + 2) % 3, (i + 2) << 5);
    short8 af[4], bfr[4];
    #pragma unroll
    for (int m = 0; m < 4; m++)
      af[m] = *(const short8*)&lA[cur][((m << 4) + la) * 64 + caA];
    #pragma unroll
    for (int n = 0; n < 4; n++)
      bfr[n] = *(const short8*)&lB[cur][((n << 4) + la) * 64 + caB];
    #pragma unroll
    for (int m = 0; m < 4; m++)
      #pragma unroll
      for (int n = 0; n < 4; n++)
        acc[m][n] = mfma16(af[m], bfr[n], acc[m][n]);
  }
  #undef STAGE

  #pragma unroll
  for (int n = 0; n < 4; n++){
    int col = colBase + bcol + (n << 4) + la;
    float bv = bias[col];
    #pragma unroll
    for (int m = 0; m < 4; m++){
      int rowT = arow + (m << 4) + (g << 2);
      #pragma unroll
      for (int rr = 0; rr < 4; rr++){
        float v = acc[m][n][rr] + bv;
        if (RELU) v = fmaxf(v, 0.f);
        if (HAS_RES) v += res[(size_t)(rowLocalBase + rowT + rr) * N + col];
        if (OUT_BF16) ((u16*)outp)[(size_t)(rowBase + rowT + rr) * N + col] = f2bf(v);
        else ((float*)outp)[(size_t)(rowBase + rowT + rr) * N + col] = v;
      }
    }
  }
}

// ---- flash cross-attention: 8 waves x 32 q-rows (2 row-groups), Q=256/block ----
// Round-13 exact (proven 98.5us): K/Vt LDS double-buffers + XCD-chunked swizzle.
__global__ __launch_bounds__(512, 4) void attn_kernel(
    const u16* __restrict__ qkv, const u16* __restrict__ vt, u16* __restrict__ fb)
{
  // chunked swizzle: logical l = (i%8)*64 + i/8; qt fastest in logical order
  int l = (blockIdx.x & 7) * 64 + (blockIdx.x >> 3);
  int qt = l & 7;                 // 0..7
  int h  = (l >> 3) & 7;          // 0..7
  int z  = l >> 6;                // dir*4 + b
  int dir = z >> 2, b = z & 3;
  int qRow0  = dir * NHALF + b * SEQ + qt * 256;
  int kvRow0 = (dir ^ 1) * NHALF + b * SEQ;
  int colQ = h * 64;

  __shared__ __align__(16) u16 lK[2][64 * 64];
  __shared__ __align__(16) u16 lVt[2][64 * 64];
  __shared__ __align__(16) u16 lP[8][32 * 64];

  int tid = threadIdx.x, wv = tid >> 6, ln = tid & 63;
  int g = ln >> 4, lo = ln & 15;

  int srow = tid >> 3;                         // 0..63
  int soff = ((tid & 7) ^ (srow & 7)) * 8;

  const float CEXP = 0.18033688f;   // 0.125 * log2(e)

  int ca0 = (g * 8) ^ ((lo & 7) << 3);
  int ca1 = (32 + g * 8) ^ ((lo & 7) << 3);
  int lo64 = lo * 64;

  int pidx[4];
  #pragma unroll
  for (int n = 0; n < 4; n++)
    pidx[n] = lo64 + ((n * 16 + g * 4) ^ ((lo & 7) << 3));
  int pra = lo64 + ca0, prb = lo64 + ca1;      // rg1 adds +1024 (16 rows)

  const u16* qbase  = qkv + (size_t)qRow0 * QKVN + colQ;
  const u16* vtbase = vt + (size_t)((dir ^ 1) * 32 + b * 8 + h) * 131072;

  const u16* kp0 = qkv + (size_t)(kvRow0 + srow) * QKVN + 512 + colQ + soff;
  const u16* vp0 = vtbase + (size_t)srow * 2048 + soff;

  char* dK0 = (char*)lK[0] + wv * 1024;
  char* dV0 = (char*)lVt[0] + wv * 1024;
  const u16* lKf = &lK[0][0];
  const u16* lVf = &lVt[0][0];
  u16* lPw = &lP[wv][0];

  // ---- prologue: Q(256x64) -> all four K/V buffers, read q frags ----
  gload_lds16(qbase + (size_t)srow * QKVN + soff,         (char*)lK[0]  + wv * 1024);
  gload_lds16(qbase + (size_t)(64 + srow) * QKVN + soff,  (char*)lK[1]  + wv * 1024);
  gload_lds16(qbase + (size_t)(128 + srow) * QKVN + soff, (char*)lVt[0] + wv * 1024);
  gload_lds16(qbase + (size_t)(192 + srow) * QKVN + soff, (char*)lVt[1] + wv * 1024);
  __syncthreads();
  const u16* qh;
  switch (wv >> 1){ case 0: qh = lK[0]; break; case 1: qh = lK[1]; break;
                    case 2: qh = lVt[0]; break; default: qh = lVt[1]; break; }
  int qr0 = (wv & 1) * 32 + lo;                // rg0 row in buffer; row&7 == lo&7
  short8 qf00 = *(const short8*)&qh[qr0 * 64 + ca0];
  short8 qf01 = *(const short8*)&qh[qr0 * 64 + ca1];
  short8 qf10 = *(const short8*)&qh[(qr0 + 16) * 64 + ca0];
  short8 qf11 = *(const short8*)&qh[(qr0 + 16) * 64 + ca1];
  __syncthreads();

  // ---- stage K(0), Vt(0) ----
  gload_lds16(kp0, dK0);
  gload_lds16(vp0, dV0);
  kp0 += (size_t)64 * QKVN; vp0 += 64;
  __syncthreads();

  f32x4 acc_o0[4], acc_o1[4];
  #pragma unroll
  for (int nd = 0; nd < 4; nd++){
    acc_o0[nd] = (f32x4){0.f, 0.f, 0.f, 0.f};
    acc_o1[nd] = (f32x4){0.f, 0.f, 0.f, 0.f};
  }
  f32x4 acc_l0 = (f32x4){0.f, 0.f, 0.f, 0.f};
  f32x4 acc_l1 = (f32x4){0.f, 0.f, 0.f, 0.f};
  float m_l0, m_l1;
  const f32x4 z4 = (f32x4){0.f, 0.f, 0.f, 0.f};

  short8 ones;
  #pragma unroll
  for (int j = 0; j < 8; j++) ones[j] = (short)0x3F80;

  int cb = 0;
  for (int t = 0; t < 32; t++){
    if (t < 31){
      int nb = cb ^ 8192;
      gload_lds16(kp0, dK0 + nb);
      gload_lds16(vp0, dV0 + nb);
      kp0 += (size_t)64 * QKVN; vp0 += 64;
    }
    const u16* lk = (const u16*)((const char*)lKf + cb);
    const u16* lv = (const u16*)((const char*)lVf + cb);

    // QK^T (swapped): K frags read once, feed both row-groups
    f32x4 s0[4], s1[4];
    #pragma unroll
    for (int n = 0; n < 4; n++){
      short8 kfa = *(const short8*)&lk[lo64 + n * 1024 + ca0];
      short8 kfb = *(const short8*)&lk[lo64 + n * 1024 + ca1];
      s0[n] = mfma16(kfa, qf00, z4);
      s0[n] = mfma16(kfb, qf01, s0[n]);
      s1[n] = mfma16(kfa, qf10, z4);
      s1[n] = mfma16(kfb, qf11, s1[n]);
    }

    // row max trees (per rgroup) + 2 shfl each
    float m00, m01;
    {
      float t0 = fmaxf(fmaxf(s0[0][0], s0[0][1]), fmaxf(s0[0][2], s0[0][3]));
      float t1 = fmaxf(fmaxf(s0[1][0], s0[1][1]), fmaxf(s0[1][2], s0[1][3]));
      float t2 = fmaxf(fmaxf(s0[2][0], s0[2][1]), fmaxf(s0[2][2], s0[2][3]));
      float t3 = fmaxf(fmaxf(s0[3][0], s0[3][1]), fmaxf(s0[3][2], s0[3][3]));
      m00 = fmaxf(fmaxf(t0, t1), fmaxf(t2, t3));
      m00 = fmaxf(m00, __shfl_xor(m00, 16, 64));
      m00 = fmaxf(m00, __shfl_xor(m00, 32, 64));
      m00 *= CEXP;
    }
    {
      float t0 = fmaxf(fmaxf(s1[0][0], s1[0][1]), fmaxf(s1[0][2], s1[0][3]));
      float t1 = fmaxf(fmaxf(s1[1][0], s1[1][1]), fmaxf(s1[1][2], s1[1][3]));
      float t2 = fmaxf(fmaxf(s1[2][0], s1[2][1]), fmaxf(s1[2][2], s1[2][3]));
      float t3 = fmaxf(fmaxf(s1[3][0], s1[3][1]), fmaxf(s1[3][2], s1[3][3]));
      m01 = fmaxf(fmaxf(t0, t1), fmaxf(t2, t3));
      m01 = fmaxf(m01, __shfl_xor(m01, 16, 64));
      m01 = fmaxf(m01, __shfl_xor(m01, 32, 64));
      m01 *= CEXP;
    }

    if (t == 0){ m_l0 = m00; m_l1 = m01; }

    // eager P with current m_l (tile 0: fresh max; t>0: old max, bounded by 2^8)
    #pragma unroll
    for (int n = 0; n < 4; n++){
      float p0 = fexp2(fmaf(s0[n][0], CEXP, -m_l0));
      float p1 = fexp2(fmaf(s0[n][1], CEXP, -m_l0));
      float p2 = fexp2(fmaf(s0[n][2], CEXP, -m_l0));
      float p3 = fexp2(fmaf(s0[n][3], CEXP, -m_l0));
      uint2 pk0; pk0.x = cvtpk(p0, p1); pk0.y = cvtpk(p2, p3);
      *(uint2*)&lPw[pidx[n]] = pk0;
      float q0 = fexp2(fmaf(s1[n][0], CEXP, -m_l1));
      float q1 = fexp2(fmaf(s1[n][1], CEXP, -m_l1));
      float q2 = fexp2(fmaf(s1[n][2], CEXP, -m_l1));
      float q3 = fexp2(fmaf(s1[n][3], CEXP, -m_l1));
      uint2 pk1; pk1.x = cvtpk(q0, q1); pk1.y = cvtpk(q2, q3);
      *(uint2*)&lPw[pidx[n] + 1024] = pk1;
    }

    // PV + row-sum; V frags read once, feed both row-groups
    short8 pf00 = *(const short8*)&lPw[pra];
    short8 pf01 = *(const short8*)&lPw[prb];
    short8 pf10 = *(const short8*)&lPw[pra + 1024];
    short8 pf11 = *(const short8*)&lPw[prb + 1024];
    acc_l0 = mfma16(pf00, ones, acc_l0);
    acc_l0 = mfma16(pf01, ones, acc_l0);
    acc_l1 = mfma16(pf10, ones, acc_l1);
    acc_l1 = mfma16(pf11, ones, acc_l1);
    #pragma unroll
    for (int nd = 0; nd < 4; nd++){
      short8 vfa = *(const short8*)&lv[lo64 + nd * 1024 + ca0];
      short8 vfb = *(const short8*)&lv[lo64 + nd * 1024 + ca1];
      acc_o0[nd] = mfma16(pf00, vfa, acc_o0[nd]);
      acc_o0[nd] = mfma16(pf01, vfb, acc_o0[nd]);
      acc_o1[nd] = mfma16(pf10, vfa, acc_o1[nd]);
      acc_o1[nd] = mfma16(pf11, vfb, acc_o1[nd]);
    }

    // deferred rescale (PV above used old m_l -> consistent)
    bool ok = (m00 <= m_l0 + 8.f) && (m01 <= m_l1 + 8.f);
    if (!__all(ok)){
      float mn0 = fmaxf(m_l0, m00);
      float mn1 = fmaxf(m_l1, m01);
      float a00 = fexp2(m_l0 - mn0);
      float a01 = fexp2(m_l1 - mn1);
      m_l0 = mn0; m_l1 = mn1;
      #pragma unroll
      for (int r = 0; r < 4; r++){
        float ar0 = __shfl(a00, g * 4 + r, 64);
        float ar1 = __shfl(a01, g * 4 + r, 64);
        acc_l0[r] *= ar0;
        acc_l1[r] *= ar1;
        #pragma unroll
        for (int nd = 0; nd < 4; nd++){
          acc_o0[nd][r] *= ar0;
          acc_o1[nd][r] *= ar1;
        }
      }
    }

    cb ^= 8192;
    __syncthreads();
  }

  #pragma unroll
  for (int r = 0; r < 4; r++){
    float rl0 = 1.0f / acc_l0[r];
    float rl1 = 1.0f / acc_l1[r];
    #pragma unroll
    for (int nd = 0; nd < 4; nd++){
      int row0 = qRow0 + wv * 32 + g * 4 + r;
      int d    = colQ + (nd << 4) + lo;
      fb[(size_t)row0 * FD + d]        = f2bf(acc_o0[nd][r] * rl0);
      fb[(size_t)(row0 + 16) * FD + d] = f2bf(acc_o1[nd][r] * rl1);
    }
  }
}

extern "C" void kernel_launch(void* const* d_in, const int* in_sizes, int n_in,
                              void* d_out, int out_size, void* d_ws, size_t ws_size,
                              hipStream_t stream)
{
  const float* t1   = (const float*)d_in[0];
  const float* t2   = (const float*)d_in[1];
  const float* ln1g = (const float*)d_in[2];
  const float* ln1b = (const float*)d_in[3];
  const float* ln2g = (const float*)d_in[4];
  const float* ln2b = (const float*)d_in[5];
  const float* Wq   = (const float*)d_in[6];
  const float* bq   = (const float*)d_in[7];
  const float* Wk   = (const float*)d_in[8];
  const float* bk   = (const float*)d_in[9];
  const float* Wv   = (const float*)d_in[10];
  const float* bv   = (const float*)d_in[11];
  const float* Wfc  = (const float*)d_in[12];
  const float* bfc  = (const float*)d_in[13];
  const float* f1lg = (const float*)d_in[14];
  const float* f1lb = (const float*)d_in[15];
  const float* W11  = (const float*)d_in[16];
  const float* b11  = (const float*)d_in[17];
  const float* W12  = (const float*)d_in[18];
  const float* b12  = (const float*)d_in[19];
  const float* f2lg = (const float*)d_in[20];
  const float* f2lb = (const float*)d_in[21];
  const float* W21  = (const float*)d_in[22];
  const float* b21  = (const float*)d_in[23];
  const float* W22  = (const float*)d_in[24];
  const float* b22  = (const float*)d_in[25];

  char* ws = (char*)d_ws;
  const size_t MB = 1024 * 1024;
  u16* wt     = (u16*)ws;                  // 8 x [512,512] bf16 (transposed)
  u16* tln    = (u16*)(ws + 4 * MB);       // [16384,512]   (dead after QKV GEMM)
  u16* qkv    = (u16*)(ws + 20 * MB);      // [16384,1536]
  u16* fb     = (u16*)(ws + 68 * MB);      // [16384,512]
  float* bqkv = (float*)(ws + 84 * MB);    // [1536]
  u16* vtb    = tln;                       // 16 MB, reuses tln (lifetime-disjoint)
  u16* xln    = tln;                       // reuse after attn
  u16* hb     = qkv;                       // reuse
  float* out  = (float*)d_out;

  wconv_kernel<<<512, 256, 0, stream>>>(Wq, Wk, Wv, Wfc, W11, W12, W21, W22, wt);
  biascat_kernel<<<6, 256, 0, stream>>>(bq, bk, bv, bqkv);
  ln_kernel<<<4096, 256, 0, stream>>>(t1, t2, ln1g, ln1b, ln2g, ln2b, tln);
  gemm_bt<false, true, false><<<1536, 256, 0, stream>>>(
      tln, wt, wt, bqkv, bqkv, nullptr, nullptr, qkv, NTOT, QKVN, FD, NTOT);
  vtr_kernel<<<1024, 256, 0, stream>>>(qkv, vtb);
  attn_kernel<<<512, 512, 0, stream>>>(qkv, vtb, fb);
  gemm_bt<false, false, true><<<512, 256, 0, stream>>>(
      fb, wt + 3 * 262144, wt + 3 * 262144, bfc, bfc, t1, t2, out, NTOT, FD, FD, NHALF);
  ln_kernel<<<4096, 256, 0, stream>>>(out, out + (size_t)NHALF * FD, f1lg, f1lb, f2lg, f2lb, xln);
  gemm_bt<true, true, false><<<512, 256, 0, stream>>>(
      xln, wt + 4 * 262144, wt + 6 * 262144, b11, b21, nullptr, nullptr, hb, NTOT, FD, FD, NHALF);
  gemm_bt<false, false, true><<<512, 256, 0, stream>>>(
      hb, wt + 5 * 262144, wt + 7 * 262144, b12, b22, out, out + (size_t)NHALF * FD, out, NTOT, FD, FD, NHALF);
}

// Round 19
// 217.950 us; speedup vs baseline: 1.0944x; 1.0292x over previous
//
#include <hip/hip_runtime.h>
#include <stdint.h>

#define FD    512
#define SEQ   2048
#define NHALF 8192
#define NTOT  16384
#define QKVN  1536

typedef unsigned short u16;
typedef __attribute__((ext_vector_type(8))) short short8;
typedef __attribute__((ext_vector_type(4))) float f32x4;

__device__ __forceinline__ u16 f2bf(float f){
  union { float f; uint32_t i; } v; v.f = f;
  uint32_t r = v.i + 0x7FFFu + ((v.i >> 16) & 1u);
  return (u16)(r >> 16);
}

__device__ __forceinline__ float bf2f(u16 u){
  union { uint32_t i; float f; } v; v.i = ((uint32_t)u) << 16; return v.f;
}

__device__ __forceinline__ void gload_lds16(const void* g, void* l){
  __builtin_amdgcn_global_load_lds((const __attribute__((address_space(1))) void*)g,
                                   (__attribute__((address_space(3))) void*)l, 16, 0, 0);
}

__device__ __forceinline__ f32x4 mfma16(short8 a, short8 b, f32x4 c){
  return __builtin_amdgcn_mfma_f32_16x16x32_bf16(a, b, c, 0, 0, 0);
}

__device__ __forceinline__ uint32_t cvtpk(float lo, float hi){
  uint32_t r; asm("v_cvt_pk_bf16_f32 %0, %1, %2" : "=v"(r) : "v"(lo), "v"(hi)); return r;
}

// single-instruction 2^x (v_exp_f32); exp2f() without fast-math is a slow OCML poly
__device__ __forceinline__ float fexp2(float x){
  float r; asm("v_exp_f32 %0, %1" : "=v"(r) : "v"(x)); return r;
}

// ---- weight convert + transpose via LDS tile: wt[mat][n][k] = bf16(w[k][n]) ----
__global__ __launch_bounds__(256) void wconv_kernel(
    const float* __restrict__ w0, const float* __restrict__ w1,
    const float* __restrict__ w2, const float* __restrict__ w3,
    const float* __restrict__ w4, const float* __restrict__ w5,
    const float* __restrict__ w6, const float* __restrict__ w7,
    u16* __restrict__ out)
{
  int mat = blockIdx.x >> 6;
  const float* w = w0;
  switch (mat){ case 1: w=w1; break; case 2: w=w2; break; case 3: w=w3; break;
                case 4: w=w4; break; case 5: w=w5; break; case 6: w=w6; break;
                case 7: w=w7; break; default: break; }
  int tile = blockIdx.x & 63;
  int k0 = (tile >> 3) << 6, n0 = (tile & 7) << 6;

  __shared__ float lt[64][65];
  int tid = threadIdx.x;
  int tr = tid >> 4, tc = (tid & 15) << 2;
  #pragma unroll
  for (int p = 0; p < 4; p++){
    int k = p * 16 + tr;
    float4 v = *(const float4*)&w[(size_t)(k0 + k) * 512 + n0 + tc];
    lt[k][tc] = v.x; lt[k][tc + 1] = v.y; lt[k][tc + 2] = v.z; lt[k][tc + 3] = v.w;
  }
  __syncthreads();
  int n = tid >> 2, kc = (tid & 3) << 4;
  u16 buf[16];
  #pragma unroll
  for (int j = 0; j < 16; j++) buf[j] = f2bf(lt[kc + j][n]);
  u16* dst = out + ((size_t)mat << 18) + (size_t)(n0 + n) * 512 + k0 + kc;
  *(short8*)dst       = *(const short8*)(buf);
  *(short8*)(dst + 8) = *(const short8*)(buf + 8);
}

__global__ __launch_bounds__(256) void biascat_kernel(
    const float* __restrict__ bq, const float* __restrict__ bk,
    const float* __restrict__ bv, float* __restrict__ o)
{
  int i = blockIdx.x * 256 + threadIdx.x;      // grid 6 -> 0..1535
  if (i < 512) o[i] = bq[i];
  else if (i < 1024) o[i] = bk[i - 512];
  else o[i] = bv[i - 1024];
}

// ---- layernorm, wave-per-row: 4 rows/block, no LDS, no barriers ----
// INBF: input rows are bf16 (the xb chain) instead of f32.
template<bool INBF>
__global__ __launch_bounds__(256) void ln_kernel(
    const void* __restrict__ xa, const void* __restrict__ xb,
    const float* __restrict__ ga, const float* __restrict__ ba,
    const float* __restrict__ gb, const float* __restrict__ bb,
    u16* __restrict__ out)
{
  int row = (blockIdx.x << 2) + (threadIdx.x >> 6);
  int ln = threadIdx.x & 63;
  const void* xp; const float* g; const float* bi; int rl;
  if (row < NHALF){ xp = xa; g = ga; bi = ba; rl = row; }
  else            { xp = xb; g = gb; bi = bb; rl = row - NHALF; }
  int c = ln << 3;
  float d[8];
  if (INBF){
    short8 s8 = *(const short8*)((const u16*)xp + (size_t)rl * FD + c);
    #pragma unroll
    for (int j = 0; j < 8; j++) d[j] = bf2f((u16)s8[j]);
  } else {
    const float* x = (const float*)xp + (size_t)rl * FD + c;
    float4 v0 = *(const float4*)x;
    float4 v1 = *(const float4*)(x + 4);
    d[0]=v0.x; d[1]=v0.y; d[2]=v0.z; d[3]=v0.w;
    d[4]=v1.x; d[5]=v1.y; d[6]=v1.z; d[7]=v1.w;
  }
  float s = (d[0] + d[1]) + (d[2] + d[3]) + (d[4] + d[5]) + (d[6] + d[7]);
  #pragma unroll
  for (int o = 32; o; o >>= 1) s += __shfl_xor(s, o, 64);
  float mu = s * (1.0f / 512.0f);
  float q = 0.f;
  #pragma unroll
  for (int j = 0; j < 8; j++){ d[j] -= mu; q += d[j] * d[j]; }
  #pragma unroll
  for (int o = 32; o; o >>= 1) q += __shfl_xor(q, o, 64);
  float rs = rsqrtf(q * (1.0f / 512.0f) + 1e-6f);
  float4 g0 = *(const float4*)&g[c],  g1 = *(const float4*)&g[c + 4];
  float4 b0 = *(const float4*)&bi[c], b1 = *(const float4*)&bi[c + 4];
  float gg[8] = {g0.x, g0.y, g0.z, g0.w, g1.x, g1.y, g1.z, g1.w};
  float bbv[8] = {b0.x, b0.y, b0.z, b0.w, b1.x, b1.y, b1.z, b1.w};
  u16 o8[8];
  #pragma unroll
  for (int j = 0; j < 8; j++) o8[j] = f2bf(d[j] * rs * gg[j] + bbv[j]);
  *(short8*)&out[(size_t)row * FD + c] = *(const short8*)o8;
}

// ---- V transpose: vt[slab][d][k] = qkv[dir*8192+b*2048+k][1024+h*64+d] ----
__global__ __launch_bounds__(256) void vtr_kernel(
    const u16* __restrict__ qkv, u16* __restrict__ vt)
{
  int kc = blockIdx.x & 15;        // k chunk of 128
  int s  = blockIdx.x >> 4;        // 0..63
  int dir = s >> 5, b = (s >> 3) & 3, h = s & 7;
  int t = threadIdx.x;
  int d = t & 63, kb = t >> 6;     // kb 0..3
  const u16* src = qkv + (size_t)(dir * NHALF + b * SEQ + kc * 128 + kb * 32) * QKVN
                       + 1024 + h * 64 + d;
  u16* dst = vt + (size_t)s * 131072 + (size_t)d * 2048 + kc * 128 + kb * 32;
  u16 buf[32];
  #pragma unroll
  for (int j = 0; j < 32; j++) buf[j] = src[(size_t)j * QKVN];
  #pragma unroll
  for (int j = 0; j < 4; j++)
    *(short8*)(dst + j * 8) = *(const short8*)(buf + j * 8);
}

// ---- GEMM: C = A[M,K] @ Bt[N,K]^T + bias (+res), 128x128 tile, BK=32 ----
// 3-deep pipeline with counted vmcnt; conflict-free [64][64] swizzled tiles.
// RES_BF16: residual buffer is bf16 (the xb chain).
template<bool RELU, bool OUT_BF16, bool HAS_RES, bool RES_BF16>
__global__ __launch_bounds__(256) void gemm_bt(
    const u16* __restrict__ A,
    const u16* __restrict__ BtLo, const u16* __restrict__ BtHi,
    const float* __restrict__ biasLo, const float* __restrict__ biasHi,
    const void* __restrict__ resLo, const void* __restrict__ resHi,
    void* __restrict__ outp,
    int M, int N, int K, int halfM)
{
  __shared__ __align__(16) u16 lA[3][64 * 64];
  __shared__ __align__(16) u16 lB[3][64 * 64];
  int nwg = gridDim.x;
  int bid = (blockIdx.x & 7) * (nwg >> 3) + (blockIdx.x >> 3);
  int nTN = N >> 7;
  int bm = bid / nTN, bn = bid - bm * nTN;
  int rowBase = bm << 7, colBase = bn << 7;
  bool inLo = rowBase < halfM;
  const u16* Bt = inLo ? BtLo : BtHi;
  const float* bias = inLo ? biasLo : biasHi;
  const void* res = inLo ? resLo : resHi;
  int rowLocalBase = inLo ? rowBase : rowBase - halfM;

  int tid = threadIdx.x, wv = tid >> 6, ln = tid & 63;
  int g = ln >> 4, la = ln & 15;

  f32x4 acc[4][4];
  #pragma unroll
  for (int m = 0; m < 4; m++)
    #pragma unroll
    for (int n = 0; n < 4; n++) acc[m][n] = (f32x4){0.f, 0.f, 0.f, 0.f};

  int r   = tid >> 3;
  int sl  = (tid & 7) ^ (r & 7);
  int shalf = sl >> 2, sk8 = (sl & 3) << 3;
  const u16* gA0 = A  + (size_t)(rowBase + r + shalf * 64) * K + sk8;
  const u16* gB0 = Bt + (size_t)(colBase + r + shalf * 64) * K + sk8;
  const size_t row32 = (size_t)32 * K;

  int caA = (((wv >> 1) << 5) + (g << 3)) ^ ((la & 7) << 3);
  int caB = (((wv & 1) << 5) + (g << 3)) ^ ((la & 7) << 3);

  int arow = (wv >> 1) << 6, bcol = (wv & 1) << 6;

  #define STAGE(buf, kt) do { \
    gload_lds16(gA0 + (kt), (char*)lA[buf] + wv * 1024); \
    gload_lds16(gA0 + (kt) + row32, (char*)lA[buf] + 4096 + wv * 1024); \
    gload_lds16(gB0 + (kt), (char*)lB[buf] + wv * 1024); \
    gload_lds16(gB0 + (kt) + row32, (char*)lB[buf] + 4096 + wv * 1024); } while (0)

  int nK = K >> 5;
  STAGE(0, 0);
  STAGE(1, 32);

  for (int i = 0; i < nK; i++){
    if (i < nK - 1) asm volatile("s_waitcnt vmcnt(4)" ::: "memory");
    else            asm volatile("s_waitcnt vmcnt(0)" ::: "memory");
    __builtin_amdgcn_s_barrier();
    __builtin_amdgcn_sched_barrier(0);
    int cur = i % 3;
    if (i + 2 < nK) STAGE((i + 2) % 3, (i + 2) << 5);
    short8 af[4], bfr[4];
    #pragma unroll
    for (int m = 0; m < 4; m++)
      af[m] = *(const short8*)&lA[cur][((m << 4) + la) * 64 + caA];
    #pragma unroll
    for (int n = 0; n < 4; n++)
      bfr[n] = *(const short8*)&lB[cur][((n << 4) + la) * 64 + caB];
    #pragma unroll
    for (int m = 0; m < 4; m++)
      #pragma unroll
      for (int n = 0; n < 4; n++)
        acc[m][n] = mfma16(af[m], bfr[n], acc[m][n]);
  }
  #undef STAGE

  #pragma unroll
  for (int n = 0; n < 4; n++){
    int col = colBase + bcol + (n << 4) + la;
    float bv = bias[col];
    #pragma unroll
    for (int m = 0; m < 4; m++){
      int rowT = arow + (m << 4) + (g << 2);
      #pragma unroll
      for (int rr = 0; rr < 4; rr++){
        float v = acc[m][n][rr] + bv;
        if (RELU) v = fmaxf(v, 0.f);
        if (HAS_RES){
          size_t ri = (size_t)(rowLocalBase + rowT + rr) * N + col;
          if (RES_BF16) v += bf2f(((const u16*)res)[ri]);
          else          v += ((const float*)res)[ri];
        }
        if (OUT_BF16) ((u16*)outp)[(size_t)(rowBase + rowT + rr) * N + col] = f2bf(v);
        else ((float*)outp)[(size_t)(rowBase + rowT + rr) * N + col] = v;
      }
    }
  }
}

// ---- flash cross-attention: 8 waves x 32 q-rows (2 row-groups), Q=256/block ----
// Round-13 exact (proven 98.5us): K/Vt LDS double-buffers + XCD-chunked swizzle.
__global__ __launch_bounds__(512, 4) void attn_kernel(
    const u16* __restrict__ qkv, const u16* __restrict__ vt, u16* __restrict__ fb)
{
  // chunked swizzle: logical l = (i%8)*64 + i/8; qt fastest in logical order
  int l = (blockIdx.x & 7) * 64 + (blockIdx.x >> 3);
  int qt = l & 7;                 // 0..7
  int h  = (l >> 3) & 7;          // 0..7
  int z  = l >> 6;                // dir*4 + b
  int dir = z >> 2, b = z & 3;
  int qRow0  = dir * NHALF + b * SEQ + qt * 256;
  int kvRow0 = (dir ^ 1) * NHALF + b * SEQ;
  int colQ = h * 64;

  __shared__ __align__(16) u16 lK[2][64 * 64];
  __shared__ __align__(16) u16 lVt[2][64 * 64];
  __shared__ __align__(16) u16 lP[8][32 * 64];

  int tid = threadIdx.x, wv = tid >> 6, ln = tid & 63;
  int g = ln >> 4, lo = ln & 15;

  int srow = tid >> 3;                         // 0..63
  int soff = ((tid & 7) ^ (srow & 7)) * 8;

  const float CEXP = 0.18033688f;   // 0.125 * log2(e)

  int ca0 = (g * 8) ^ ((lo & 7) << 3);
  int ca1 = (32 + g * 8) ^ ((lo & 7) << 3);
  int lo64 = lo * 64;

  int pidx[4];
  #pragma unroll
  for (int n = 0; n < 4; n++)
    pidx[n] = lo64 + ((n * 16 + g * 4) ^ ((lo & 7) << 3));
  int pra = lo64 + ca0, prb = lo64 + ca1;      // rg1 adds +1024 (16 rows)

  const u16* qbase  = qkv + (size_t)qRow0 * QKVN + colQ;
  const u16* vtbase = vt + (size_t)((dir ^ 1) * 32 + b * 8 + h) * 131072;

  const u16* kp0 = qkv + (size_t)(kvRow0 + srow) * QKVN + 512 + colQ + soff;
  const u16* vp0 = vtbase + (size_t)srow * 2048 + soff;

  char* dK0 = (char*)lK[0] + wv * 1024;
  char* dV0 = (char*)lVt[0] + wv * 1024;
  const u16* lKf = &lK[0][0];
  const u16* lVf = &lVt[0][0];
  u16* lPw = &lP[wv][0];

  // ---- prologue: Q(256x64) -> all four K/V buffers, read q frags ----
  gload_lds16(qbase + (size_t)srow * QKVN + soff,         (char*)lK[0]  + wv * 1024);
  gload_lds16(qbase + (size_t)(64 + srow) * QKVN + soff,  (char*)lK[1]  + wv * 1024);
  gload_lds16(qbase + (size_t)(128 + srow) * QKVN + soff, (char*)lVt[0] + wv * 1024);
  gload_lds16(qbase + (size_t)(192 + srow) * QKVN + soff, (char*)lVt[1] + wv * 1024);
  __syncthreads();
  const u16* qh;
  switch (wv >> 1){ case 0: qh = lK[0]; break; case 1: qh = lK[1]; break;
                    case 2: qh = lVt[0]; break; default: qh = lVt[1]; break; }
  int qr0 = (wv & 1) * 32 + lo;                // rg0 row in buffer; row&7 == lo&7
  short8 qf00 = *(const short8*)&qh[qr0 * 64 + ca0];
  short8 qf01 = *(const short8*)&qh[qr0 * 64 + ca1];
  short8 qf10 = *(const short8*)&qh[(qr0 + 16) * 64 + ca0];
  short8 qf11 = *(const short8*)&qh[(qr0 + 16) * 64 + ca1];
  __syncthreads();

  // ---- stage K(0), Vt(0) ----
  gload_lds16(kp0, dK0);
  gload_lds16(vp0, dV0);
  kp0 += (size_t)64 * QKVN; vp0 += 64;
  __syncthreads();

  f32x4 acc_o0[4], acc_o1[4];
  #pragma unroll
  for (int nd = 0; nd < 4; nd++){
    acc_o0[nd] = (f32x4){0.f, 0.f, 0.f, 0.f};
    acc_o1[nd] = (f32x4){0.f, 0.f, 0.f, 0.f};
  }
  f32x4 acc_l0 = (f32x4){0.f, 0.f, 0.f, 0.f};
  f32x4 acc_l1 = (f32x4){0.f, 0.f, 0.f, 0.f};
  float m_l0, m_l1;
  const f32x4 z4 = (f32x4){0.f, 0.f, 0.f, 0.f};

  short8 ones;
  #pragma unroll
  for (int j = 0; j < 8; j++) ones[j] = (short)0x3F80;

  int cb = 0;
  for (int t = 0; t < 32; t++){
    if (t < 31){
      int nb = cb ^ 8192;
      gload_lds16(kp0, dK0 + nb);
      gload_lds16(vp0, dV0 + nb);
      kp0 += (size_t)64 * QKVN; vp0 += 64;
    }
    const u16* lk = (const u16*)((const char*)lKf + cb);
    const u16* lv = (const u16*)((const char*)lVf + cb);

    // QK^T (swapped): K frags read once, feed both row-groups
    f32x4 s0[4], s1[4];
    #pragma unroll
    for (int n = 0; n < 4; n++){
      short8 kfa = *(const short8*)&lk[lo64 + n * 1024 + ca0];
      short8 kfb = *(const short8*)&lk[lo64 + n * 1024 + ca1];
      s0[n] = mfma16(kfa, qf00, z4);
      s0[n] = mfma16(kfb, qf01, s0[n]);
      s1[n] = mfma16(kfa, qf10, z4);
      s1[n] = mfma16(kfb, qf11, s1[n]);
    }

    // row max trees (per rgroup) + 2 shfl each
    float m00, m01;
    {
      float t0 = fmaxf(fmaxf(s0[0][0], s0[0][1]), fmaxf(s0[0][2], s0[0][3]));
      float t1 = fmaxf(fmaxf(s0[1][0], s0[1][1]), fmaxf(s0[1][2], s0[1][3]));
      float t2 = fmaxf(fmaxf(s0[2][0], s0[2][1]), fmaxf(s0[2][2], s0[2][3]));
      float t3 = fmaxf(fmaxf(s0[3][0], s0[3][1]), fmaxf(s0[3][2], s0[3][3]));
      m00 = fmaxf(fmaxf(t0, t1), fmaxf(t2, t3));
      m00 = fmaxf(m00, __shfl_xor(m00, 16, 64));
      m00 = fmaxf(m00, __shfl_xor(m00, 32, 64));
      m00 *= CEXP;
    }
    {
      float t0 = fmaxf(fmaxf(s1[0][0], s1[0][1]), fmaxf(s1[0][2], s1[0][3]));
      float t1 = fmaxf(fmaxf(s1[1][0], s1[1][1]), fmaxf(s1[1][2], s1[1][3]));
      float t2 = fmaxf(fmaxf(s1[2][0], s1[2][1]), fmaxf(s1[2][2], s1[2][3]));
      float t3 = fmaxf(fmaxf(s1[3][0], s1[3][1]), fmaxf(s1[3][2], s1[3][3]));
      m01 = fmaxf(fmaxf(t0, t1), fmaxf(t2, t3));
      m01 = fmaxf(m01, __shfl_xor(m01, 16, 64));
      m01 = fmaxf(m01, __shfl_xor(m01, 32, 64));
      m01 *= CEXP;
    }

    if (t == 0){ m_l0 = m00; m_l1 = m01; }

    // eager P with current m_l (tile 0: fresh max; t>0: old max, bounded by 2^8)
    #pragma unroll
    for (int n = 0; n < 4; n++){
      float p0 = fexp2(fmaf(s0[n][0], CEXP, -m_l0));
      float p1 = fexp2(fmaf(s0[n][1], CEXP, -m_l0));
      float p2 = fexp2(fmaf(s0[n][2], CEXP, -m_l0));
      float p3 = fexp2(fmaf(s0[n][3], CEXP, -m_l0));
      uint2 pk0; pk0.x = cvtpk(p0, p1); pk0.y = cvtpk(p2, p3);
      *(uint2*)&lPw[pidx[n]] = pk0;
      float q0 = fexp2(fmaf(s1[n][0], CEXP, -m_l1));
      float q1 = fexp2(fmaf(s1[n][1], CEXP, -m_l1));
      float q2 = fexp2(fmaf(s1[n][2], CEXP, -m_l1));
      float q3 = fexp2(fmaf(s1[n][3], CEXP, -m_l1));
      uint2 pk1; pk1.x = cvtpk(q0, q1); pk1.y = cvtpk(q2, q3);
      *(uint2*)&lPw[pidx[n] + 1024] = pk1;
    }

    // PV + row-sum; V frags read once, feed both row-groups
    short8 pf00 = *(const short8*)&lPw[pra];
    short8 pf01 = *(const short8*)&lPw[prb];
    short8 pf10 = *(const short8*)&lPw[pra + 1024];
    short8 pf11 = *(const short8*)&lPw[prb + 1024];
    acc_l0 = mfma16(pf00, ones, acc_l0);
    acc_l0 = mfma16(pf01, ones, acc_l0);
    acc_l1 = mfma16(pf10, ones, acc_l1);
    acc_l1 = mfma16(pf11, ones, acc_l1);
    #pragma unroll
    for (int nd = 0; nd < 4; nd++){
      short8 vfa = *(const short8*)&lv[lo64 + nd * 1024 + ca0];
      short8 vfb = *(const short8*)&lv[lo64 + nd * 1024 + ca1];
      acc_o0[nd] = mfma16(pf00, vfa, acc_o0[nd]);
      acc_o0[nd] = mfma16(pf01, vfb, acc_o0[nd]);
      acc_o1[nd] = mfma16(pf10, vfa, acc_o1[nd]);
      acc_o1[nd] = mfma16(pf11, vfb, acc_o1[nd]);
    }

    // deferred rescale (PV above used old m_l -> consistent)
    bool ok = (m00 <= m_l0 + 8.f) && (m01 <= m_l1 + 8.f);
    if (!__all(ok)){
      float mn0 = fmaxf(m_l0, m00);
      float mn1 = fmaxf(m_l1, m01);
      float a00 = fexp2(m_l0 - mn0);
      float a01 = fexp2(m_l1 - mn1);
      m_l0 = mn0; m_l1 = mn1;
      #pragma unroll
      for (int r = 0; r < 4; r++){
        float ar0 = __shfl(a00, g * 4 + r, 64);
        float ar1 = __shfl(a01, g * 4 + r, 64);
        acc_l0[r] *= ar0;
        acc_l1[r] *= ar1;
        #pragma unroll
        for (int nd = 0; nd < 4; nd++){
          acc_o0[nd][r] *= ar0;
          acc_o1[nd][r] *= ar1;
        }
      }
    }

    cb ^= 8192;
    __syncthreads();
  }

  #pragma unroll
  for (int r = 0; r < 4; r++){
    float rl0 = 1.0f / acc_l0[r];
    float rl1 = 1.0f / acc_l1[r];
    #pragma unroll
    for (int nd = 0; nd < 4; nd++){
      int row0 = qRow0 + wv * 32 + g * 4 + r;
      int d    = colQ + (nd << 4) + lo;
      fb[(size_t)row0 * FD + d]        = f2bf(acc_o0[nd][r] * rl0);
      fb[(size_t)(row0 + 16) * FD + d] = f2bf(acc_o1[nd][r] * rl1);
    }
  }
}

extern "C" void kernel_launch(void* const* d_in, const int* in_sizes, int n_in,
                              void* d_out, int out_size, void* d_ws, size_t ws_size,
                              hipStream_t stream)
{
  const float* t1   = (const float*)d_in[0];
  const float* t2   = (const float*)d_in[1];
  const float* ln1g = (const float*)d_in[2];
  const float* ln1b = (const float*)d_in[3];
  const float* ln2g = (const float*)d_in[4];
  const float* ln2b = (const float*)d_in[5];
  const float* Wq   = (const float*)d_in[6];
  const float* bq   = (const float*)d_in[7];
  const float* Wk   = (const float*)d_in[8];
  const float* bk   = (const float*)d_in[9];
  const float* Wv   = (const float*)d_in[10];
  const float* bv   = (const float*)d_in[11];
  const float* Wfc  = (const float*)d_in[12];
  const float* bfc  = (const float*)d_in[13];
  const float* f1lg = (const float*)d_in[14];
  const float* f1lb = (const float*)d_in[15];
  const float* W11  = (const float*)d_in[16];
  const float* b11  = (const float*)d_in[17];
  const float* W12  = (const float*)d_in[18];
  const float* b12  = (const float*)d_in[19];
  const float* f2lg = (const float*)d_in[20];
  const float* f2lb = (const float*)d_in[21];
  const float* W21  = (const float*)d_in[22];
  const float* b21  = (const float*)d_in[23];
  const float* W22  = (const float*)d_in[24];
  const float* b22  = (const float*)d_in[25];

  char* ws = (char*)d_ws;
  const size_t MB = 1024 * 1024;
  u16* wt     = (u16*)ws;                  // 8 x [512,512] bf16 (transposed)
  u16* tln    = (u16*)(ws + 4 * MB);       // [16384,512]   (dead after QKV GEMM)
  u16* qkv    = (u16*)(ws + 20 * MB);      // [16384,1536]  (dead after attn)
  u16* fb     = (u16*)(ws + 68 * MB);      // [16384,512]
  float* bqkv = (float*)(ws + 84 * MB);    // [1536]
  u16* vtb    = tln;                       // 16 MB, reuses tln (lifetime-disjoint)
  u16* xln    = tln;                       // reuse after attn
  u16* hb     = qkv;                       // ff1 out: first 16MB of dead qkv
  u16* xb     = (u16*)(ws + 36 * MB);      // x as bf16: next 16MB of dead qkv
  float* out  = (float*)d_out;

  wconv_kernel<<<512, 256, 0, stream>>>(Wq, Wk, Wv, Wfc, W11, W12, W21, W22, wt);
  biascat_kernel<<<6, 256, 0, stream>>>(bq, bk, bv, bqkv);
  ln_kernel<false><<<4096, 256, 0, stream>>>(t1, t2, ln1g, ln1b, ln2g, ln2b, tln);
  gemm_bt<false, true, false, false><<<1536, 256, 0, stream>>>(
      tln, wt, wt, bqkv, bqkv, nullptr, nullptr, qkv, NTOT, QKVN, FD, NTOT);
  vtr_kernel<<<1024, 256, 0, stream>>>(qkv, vtb);
  attn_kernel<<<512, 512, 0, stream>>>(qkv, vtb, fb);
  gemm_bt<false, true, true, false><<<512, 256, 0, stream>>>(
      fb, wt + 3 * 262144, wt + 3 * 262144, bfc, bfc, t1, t2, xb, NTOT, FD, FD, NHALF);
  ln_kernel<true><<<4096, 256, 0, stream>>>(xb, xb + (size_t)NHALF * FD,
      f1lg, f1lb, f2lg, f2lb, xln);
  gemm_bt<true, true, false, false><<<512, 256, 0, stream>>>(
      xln, wt + 4 * 262144, wt + 6 * 262144, b11, b21, nullptr, nullptr, hb, NTOT, FD, FD, NHALF);
  gemm_bt<false, false, true, true><<<512, 256, 0, stream>>>(
      hb, wt + 5 * 262144, wt + 7 * 262144, b12, b22, xb, xb + (size_t)NHALF * FD,
      out, NTOT, FD, FD, NHALF);
}

// Round 20
// 210.009 us; speedup vs baseline: 1.1358x; 1.0378x over previous
//
#include <hip/hip_runtime.h>
#include <stdint.h>

#define FD    512
#define SEQ   2048
#define NHALF 8192
#define NTOT  16384
#define QKVN  1536

typedef unsigned short u16;
typedef __attribute__((ext_vector_type(8))) short short8;
typedef __attribute__((ext_vector_type(4))) float f32x4;

__device__ __forceinline__ u16 f2bf(float f){
  union { float f; uint32_t i; } v; v.f = f;
  uint32_t r = v.i + 0x7FFFu + ((v.i >> 16) & 1u);
  return (u16)(r >> 16);
}

__device__ __forceinline__ float bf2f(u16 u){
  union { uint32_t i; float f; } v; v.i = ((uint32_t)u) << 16; return v.f;
}

__device__ __forceinline__ void gload_lds16(const void* g, void* l){
  __builtin_amdgcn_global_load_lds((const __attribute__((address_space(1))) void*)g,
                                   (__attribute__((address_space(3))) void*)l, 16, 0, 0);
}

__device__ __forceinline__ f32x4 mfma16(short8 a, short8 b, f32x4 c){
  return __builtin_amdgcn_mfma_f32_16x16x32_bf16(a, b, c, 0, 0, 0);
}

__device__ __forceinline__ uint32_t cvtpk(float lo, float hi){
  uint32_t r; asm("v_cvt_pk_bf16_f32 %0, %1, %2" : "=v"(r) : "v"(lo), "v"(hi)); return r;
}

// single-instruction 2^x (v_exp_f32); exp2f() without fast-math is a slow OCML poly
__device__ __forceinline__ float fexp2(float x){
  float r; asm("v_exp_f32 %0, %1" : "=v"(r) : "v"(x)); return r;
}

// ---- weight convert + transpose via LDS tile: wt[mat][n][k] = bf16(w[k][n]) ----
__global__ __launch_bounds__(256) void wconv_kernel(
    const float* __restrict__ w0, const float* __restrict__ w1,
    const float* __restrict__ w2, const float* __restrict__ w3,
    const float* __restrict__ w4, const float* __restrict__ w5,
    const float* __restrict__ w6, const float* __restrict__ w7,
    u16* __restrict__ out)
{
  int mat = blockIdx.x >> 6;
  const float* w = w0;
  switch (mat){ case 1: w=w1; break; case 2: w=w2; break; case 3: w=w3; break;
                case 4: w=w4; break; case 5: w=w5; break; case 6: w=w6; break;
                case 7: w=w7; break; default: break; }
  int tile = blockIdx.x & 63;
  int k0 = (tile >> 3) << 6, n0 = (tile & 7) << 6;

  __shared__ float lt[64][65];
  int tid = threadIdx.x;
  int tr = tid >> 4, tc = (tid & 15) << 2;
  #pragma unroll
  for (int p = 0; p < 4; p++){
    int k = p * 16 + tr;
    float4 v = *(const float4*)&w[(size_t)(k0 + k) * 512 + n0 + tc];
    lt[k][tc] = v.x; lt[k][tc + 1] = v.y; lt[k][tc + 2] = v.z; lt[k][tc + 3] = v.w;
  }
  __syncthreads();
  int n = tid >> 2, kc = (tid & 3) << 4;
  u16 buf[16];
  #pragma unroll
  for (int j = 0; j < 16; j++) buf[j] = f2bf(lt[kc + j][n]);
  u16* dst = out + ((size_t)mat << 18) + (size_t)(n0 + n) * 512 + k0 + kc;
  *(short8*)dst       = *(const short8*)(buf);
  *(short8*)(dst + 8) = *(const short8*)(buf + 8);
}

__global__ __launch_bounds__(256) void biascat_kernel(
    const float* __restrict__ bq, const float* __restrict__ bk,
    const float* __restrict__ bv, float* __restrict__ o)
{
  int i = blockIdx.x * 256 + threadIdx.x;      // grid 6 -> 0..1535
  if (i < 512) o[i] = bq[i];
  else if (i < 1024) o[i] = bk[i - 512];
  else o[i] = bv[i - 1024];
}

// ---- layernorm, wave-per-row: 4 rows/block, no LDS, no barriers ----
// INBF: input rows are bf16 (the xb chain) instead of f32.
template<bool INBF>
__global__ __launch_bounds__(256) void ln_kernel(
    const void* __restrict__ xa, const void* __restrict__ xb,
    const float* __restrict__ ga, const float* __restrict__ ba,
    const float* __restrict__ gb, const float* __restrict__ bb,
    u16* __restrict__ out)
{
  int row = (blockIdx.x << 2) + (threadIdx.x >> 6);
  int ln = threadIdx.x & 63;
  const void* xp; const float* g; const float* bi; int rl;
  if (row < NHALF){ xp = xa; g = ga; bi = ba; rl = row; }
  else            { xp = xb; g = gb; bi = bb; rl = row - NHALF; }
  int c = ln << 3;
  float d[8];
  if (INBF){
    short8 s8 = *(const short8*)((const u16*)xp + (size_t)rl * FD + c);
    #pragma unroll
    for (int j = 0; j < 8; j++) d[j] = bf2f((u16)s8[j]);
  } else {
    const float* x = (const float*)xp + (size_t)rl * FD + c;
    float4 v0 = *(const float4*)x;
    float4 v1 = *(const float4*)(x + 4);
    d[0]=v0.x; d[1]=v0.y; d[2]=v0.z; d[3]=v0.w;
    d[4]=v1.x; d[5]=v1.y; d[6]=v1.z; d[7]=v1.w;
  }
  float s = (d[0] + d[1]) + (d[2] + d[3]) + (d[4] + d[5]) + (d[6] + d[7]);
  #pragma unroll
  for (int o = 32; o; o >>= 1) s += __shfl_xor(s, o, 64);
  float mu = s * (1.0f / 512.0f);
  float q = 0.f;
  #pragma unroll
  for (int j = 0; j < 8; j++){ d[j] -= mu; q += d[j] * d[j]; }
  #pragma unroll
  for (int o = 32; o; o >>= 1) q += __shfl_xor(q, o, 64);
  float rs = rsqrtf(q * (1.0f / 512.0f) + 1e-6f);
  float4 g0 = *(const float4*)&g[c],  g1 = *(const float4*)&g[c + 4];
  float4 b0 = *(const float4*)&bi[c], b1 = *(const float4*)&bi[c + 4];
  float gg[8] = {g0.x, g0.y, g0.z, g0.w, g1.x, g1.y, g1.z, g1.w};
  float bbv[8] = {b0.x, b0.y, b0.z, b0.w, b1.x, b1.y, b1.z, b1.w};
  u16 o8[8];
  #pragma unroll
  for (int j = 0; j < 8; j++) o8[j] = f2bf(d[j] * rs * gg[j] + bbv[j]);
  *(short8*)&out[(size_t)row * FD + c] = *(const short8*)o8;
}

// ---- GEMM: C = A[M,K] @ Bt[N,K]^T + bias (+res), 128x128 tile, BK=32 ----
// 3-deep pipeline with counted vmcnt; conflict-free [64][64] swizzled tiles.
// RES_BF16: residual buffer is bf16. QKV_VT: for cols >= 1024 (the V section
// of the QKV GEMM), write TRANSPOSED into the vt slab layout instead of qkv
// (fuses the former vtr kernel; k-quads are contiguous -> one 8B store).
template<bool RELU, bool OUT_BF16, bool HAS_RES, bool RES_BF16, bool QKV_VT>
__global__ __launch_bounds__(256) void gemm_bt(
    const u16* __restrict__ A,
    const u16* __restrict__ BtLo, const u16* __restrict__ BtHi,
    const float* __restrict__ biasLo, const float* __restrict__ biasHi,
    const void* __restrict__ resLo, const void* __restrict__ resHi,
    void* __restrict__ outp, u16* __restrict__ vtp,
    int M, int N, int K, int halfM)
{
  __shared__ __align__(16) u16 lA[3][64 * 64];
  __shared__ __align__(16) u16 lB[3][64 * 64];
  int nwg = gridDim.x;
  int bid = (blockIdx.x & 7) * (nwg >> 3) + (blockIdx.x >> 3);
  int nTN = N >> 7;
  int bm = bid / nTN, bn = bid - bm * nTN;
  int rowBase = bm << 7, colBase = bn << 7;
  bool inLo = rowBase < halfM;
  const u16* Bt = inLo ? BtLo : BtHi;
  const float* bias = inLo ? biasLo : biasHi;
  const void* res = inLo ? resLo : resHi;
  int rowLocalBase = inLo ? rowBase : rowBase - halfM;

  int tid = threadIdx.x, wv = tid >> 6, ln = tid & 63;
  int g = ln >> 4, la = ln & 15;

  f32x4 acc[4][4];
  #pragma unroll
  for (int m = 0; m < 4; m++)
    #pragma unroll
    for (int n = 0; n < 4; n++) acc[m][n] = (f32x4){0.f, 0.f, 0.f, 0.f};

  int r   = tid >> 3;
  int sl  = (tid & 7) ^ (r & 7);
  int shalf = sl >> 2, sk8 = (sl & 3) << 3;
  const u16* gA0 = A  + (size_t)(rowBase + r + shalf * 64) * K + sk8;
  const u16* gB0 = Bt + (size_t)(colBase + r + shalf * 64) * K + sk8;
  const size_t row32 = (size_t)32 * K;

  int caA = (((wv >> 1) << 5) + (g << 3)) ^ ((la & 7) << 3);
  int caB = (((wv & 1) << 5) + (g << 3)) ^ ((la & 7) << 3);

  int arow = (wv >> 1) << 6, bcol = (wv & 1) << 6;

  #define STAGE(buf, kt) do { \
    gload_lds16(gA0 + (kt), (char*)lA[buf] + wv * 1024); \
    gload_lds16(gA0 + (kt) + row32, (char*)lA[buf] + 4096 + wv * 1024); \
    gload_lds16(gB0 + (kt), (char*)lB[buf] + wv * 1024); \
    gload_lds16(gB0 + (kt) + row32, (char*)lB[buf] + 4096 + wv * 1024); } while (0)

  int nK = K >> 5;
  STAGE(0, 0);
  STAGE(1, 32);

  for (int i = 0; i < nK; i++){
    if (i < nK - 1) asm volatile("s_waitcnt vmcnt(4)" ::: "memory");
    else            asm volatile("s_waitcnt vmcnt(0)" ::: "memory");
    __builtin_amdgcn_s_barrier();
    __builtin_amdgcn_sched_barrier(0);
    int cur = i % 3;
    if (i + 2 < nK) STAGE((i + 2) % 3, (i + 2) << 5);
    short8 af[4], bfr[4];
    #pragma unroll
    for (int m = 0; m < 4; m++)
      af[m] = *(const short8*)&lA[cur][((m << 4) + la) * 64 + caA];
    #pragma unroll
    for (int n = 0; n < 4; n++)
      bfr[n] = *(const short8*)&lB[cur][((n << 4) + la) * 64 + caB];
    #pragma unroll
    for (int m = 0; m < 4; m++)
      #pragma unroll
      for (int n = 0; n < 4; n++)
        acc[m][n] = mfma16(af[m], bfr[n], acc[m][n]);
  }
  #undef STAGE

  #pragma unroll
  for (int n = 0; n < 4; n++){
    int col = colBase + bcol + (n << 4) + la;
    float bv = bias[col];
    #pragma unroll
    for (int m = 0; m < 4; m++){
      int rowT = arow + (m << 4) + (g << 2);
      float v4[4];
      #pragma unroll
      for (int rr = 0; rr < 4; rr++){
        float v = acc[m][n][rr] + bv;
        if (RELU) v = fmaxf(v, 0.f);
        if (HAS_RES){
          size_t ri = (size_t)(rowLocalBase + rowT + rr) * N + col;
          if (RES_BF16) v += bf2f(((const u16*)res)[ri]);
          else          v += ((const float*)res)[ri];
        }
        v4[rr] = v;
      }
      if (QKV_VT && col >= 1024){
        // transposed V write: vt[slab][d][k], 4 consecutive k -> one 8B store
        int cv = col - 1024;
        int rowA = rowBase + rowT;              // rr-quad shares slab & d
        int slab = ((rowA >= NHALF) ? 32 : 0) + (((rowA >> 11) & 3) << 3) + (cv >> 6);
        uint2 w; w.x = cvtpk(v4[0], v4[1]); w.y = cvtpk(v4[2], v4[3]);
        *(uint2*)&vtp[(size_t)slab * 131072 + (size_t)(cv & 63) * 2048 + (rowA & 2047)] = w;
      } else {
        #pragma unroll
        for (int rr = 0; rr < 4; rr++){
          if (OUT_BF16) ((u16*)outp)[(size_t)(rowBase + rowT + rr) * N + col] = f2bf(v4[rr]);
          else ((float*)outp)[(size_t)(rowBase + rowT + rr) * N + col] = v4[rr];
        }
      }
    }
  }
}

// ---- flash cross-attention: 8 waves x 32 q-rows (2 row-groups), Q=256/block ----
// Round-13 exact (proven 98.5us): K/Vt LDS double-buffers + XCD-chunked swizzle.
__global__ __launch_bounds__(512, 4) void attn_kernel(
    const u16* __restrict__ qkv, const u16* __restrict__ vt, u16* __restrict__ fb)
{
  // chunked swizzle: logical l = (i%8)*64 + i/8; qt fastest in logical order
  int l = (blockIdx.x & 7) * 64 + (blockIdx.x >> 3);
  int qt = l & 7;                 // 0..7
  int h  = (l >> 3) & 7;          // 0..7
  int z  = l >> 6;                // dir*4 + b
  int dir = z >> 2, b = z & 3;
  int qRow0  = dir * NHALF + b * SEQ + qt * 256;
  int kvRow0 = (dir ^ 1) * NHALF + b * SEQ;
  int colQ = h * 64;

  __shared__ __align__(16) u16 lK[2][64 * 64];
  __shared__ __align__(16) u16 lVt[2][64 * 64];
  __shared__ __align__(16) u16 lP[8][32 * 64];

  int tid = threadIdx.x, wv = tid >> 6, ln = tid & 63;
  int g = ln >> 4, lo = ln & 15;

  int srow = tid >> 3;                         // 0..63
  int soff = ((tid & 7) ^ (srow & 7)) * 8;

  const float CEXP = 0.18033688f;   // 0.125 * log2(e)

  int ca0 = (g * 8) ^ ((lo & 7) << 3);
  int ca1 = (32 + g * 8) ^ ((lo & 7) << 3);
  int lo64 = lo * 64;

  int pidx[4];
  #pragma unroll
  for (int n = 0; n < 4; n++)
    pidx[n] = lo64 + ((n * 16 + g * 4) ^ ((lo & 7) << 3));
  int pra = lo64 + ca0, prb = lo64 + ca1;      // rg1 adds +1024 (16 rows)

  const u16* qbase  = qkv + (size_t)qRow0 * QKVN + colQ;
  const u16* vtbase = vt + (size_t)((dir ^ 1) * 32 + b * 8 + h) * 131072;

  const u16* kp0 = qkv + (size_t)(kvRow0 + srow) * QKVN + 512 + colQ + soff;
  const u16* vp0 = vtbase + (size_t)srow * 2048 + soff;

  char* dK0 = (char*)lK[0] + wv * 1024;
  char* dV0 = (char*)lVt[0] + wv * 1024;
  const u16* lKf = &lK[0][0];
  const u16* lVf = &lVt[0][0];
  u16* lPw = &lP[wv][0];

  // ---- prologue: Q(256x64) -> all four K/V buffers, read q frags ----
  gload_lds16(qbase + (size_t)srow * QKVN + soff,         (char*)lK[0]  + wv * 1024);
  gload_lds16(qbase + (size_t)(64 + srow) * QKVN + soff,  (char*)lK[1]  + wv * 1024);
  gload_lds16(qbase + (size_t)(128 + srow) * QKVN + soff, (char*)lVt[0] + wv * 1024);
  gload_lds16(qbase + (size_t)(192 + srow) * QKVN + soff, (char*)lVt[1] + wv * 1024);
  __syncthreads();
  const u16* qh;
  switch (wv >> 1){ case 0: qh = lK[0]; break; case 1: qh = lK[1]; break;
                    case 2: qh = lVt[0]; break; default: qh = lVt[1]; break; }
  int qr0 = (wv & 1) * 32 + lo;                // rg0 row in buffer; row&7 == lo&7
  short8 qf00 = *(const short8*)&qh[qr0 * 64 + ca0];
  short8 qf01 = *(const short8*)&qh[qr0 * 64 + ca1];
  short8 qf10 = *(const short8*)&qh[(qr0 + 16) * 64 + ca0];
  short8 qf11 = *(const short8*)&qh[(qr0 + 16) * 64 + ca1];
  __syncthreads();

  // ---- stage K(0), Vt(0) ----
  gload_lds16(kp0, dK0);
  gload_lds16(vp0, dV0);
  kp0 += (size_t)64 * QKVN; vp0 += 64;
  __syncthreads();

  f32x4 acc_o0[4], acc_o1[4];
  #pragma unroll
  for (int nd = 0; nd < 4; nd++){
    acc_o0[nd] = (f32x4){0.f, 0.f, 0.f, 0.f};
    acc_o1[nd] = (f32x4){0.f, 0.f, 0.f, 0.f};
  }
  f32x4 acc_l0 = (f32x4){0.f, 0.f, 0.f, 0.f};
  f32x4 acc_l1 = (f32x4){0.f, 0.f, 0.f, 0.f};
  float m_l0, m_l1;
  const f32x4 z4 = (f32x4){0.f, 0.f, 0.f, 0.f};

  short8 ones;
  #pragma unroll
  for (int j = 0; j < 8; j++) ones[j] = (short)0x3F80;

  int cb = 0;
  for (int t = 0; t < 32; t++){
    if (t < 31){
      int nb = cb ^ 8192;
      gload_lds16(kp0, dK0 + nb);
      gload_lds16(vp0, dV0 + nb);
      kp0 += (size_t)64 * QKVN; vp0 += 64;
    }
    const u16* lk = (const u16*)((const char*)lKf + cb);
    const u16* lv = (const u16*)((const char*)lVf + cb);

    // QK^T (swapped): K frags read once, feed both row-groups
    f32x4 s0[4], s1[4];
    #pragma unroll
    for (int n = 0; n < 4; n++){
      short8 kfa = *(const short8*)&lk[lo64 + n * 1024 + ca0];
      short8 kfb = *(const short8*)&lk[lo64 + n * 1024 + ca1];
      s0[n] = mfma16(kfa, qf00, z4);
      s0[n] = mfma16(kfb, qf01, s0[n]);
      s1[n] = mfma16(kfa, qf10, z4);
      s1[n] = mfma16(kfb, qf11, s1[n]);
    }

    // row max trees (per rgroup) + 2 shfl each
    float m00, m01;
    {
      float t0 = fmaxf(fmaxf(s0[0][0], s0[0][1]), fmaxf(s0[0][2], s0[0][3]));
      float t1 = fmaxf(fmaxf(s0[1][0], s0[1][1]), fmaxf(s0[1][2], s0[1][3]));
      float t2 = fmaxf(fmaxf(s0[2][0], s0[2][1]), fmaxf(s0[2][2], s0[2][3]));
      float t3 = fmaxf(fmaxf(s0[3][0], s0[3][1]), fmaxf(s0[3][2], s0[3][3]));
      m00 = fmaxf(fmaxf(t0, t1), fmaxf(t2, t3));
      m00 = fmaxf(m00, __shfl_xor(m00, 16, 64));
      m00 = fmaxf(m00, __shfl_xor(m00, 32, 64));
      m00 *= CEXP;
    }
    {
      float t0 = fmaxf(fmaxf(s1[0][0], s1[0][1]), fmaxf(s1[0][2], s1[0][3]));
      float t1 = fmaxf(fmaxf(s1[1][0], s1[1][1]), fmaxf(s1[1][2], s1[1][3]));
      float t2 = fmaxf(fmaxf(s1[2][0], s1[2][1]), fmaxf(s1[2][2], s1[2][3]));
      float t3 = fmaxf(fmaxf(s1[3][0], s1[3][1]), fmaxf(s1[3][2], s1[3][3]));
      m01 = fmaxf(fmaxf(t0, t1), fmaxf(t2, t3));
      m01 = fmaxf(m01, __shfl_xor(m01, 16, 64));
      m01 = fmaxf(m01, __shfl_xor(m01, 32, 64));
      m01 *= CEXP;
    }

    if (t == 0){ m_l0 = m00; m_l1 = m01; }

    // eager P with current m_l (tile 0: fresh max; t>0: old max, bounded by 2^8)
    #pragma unroll
    for (int n = 0; n < 4; n++){
      float p0 = fexp2(fmaf(s0[n][0], CEXP, -m_l0));
      float p1 = fexp2(fmaf(s0[n][1], CEXP, -m_l0));
      float p2 = fexp2(fmaf(s0[n][2], CEXP, -m_l0));
      float p3 = fexp2(fmaf(s0[n][3], CEXP, -m_l0));
      uint2 pk0; pk0.x = cvtpk(p0, p1); pk0.y = cvtpk(p2, p3);
      *(uint2*)&lPw[pidx[n]] = pk0;
      float q0 = fexp2(fmaf(s1[n][0], CEXP, -m_l1));
      float q1 = fexp2(fmaf(s1[n][1], CEXP, -m_l1));
      float q2 = fexp2(fmaf(s1[n][2], CEXP, -m_l1));
      float q3 = fexp2(fmaf(s1[n][3], CEXP, -m_l1));
      uint2 pk1; pk1.x = cvtpk(q0, q1); pk1.y = cvtpk(q2, q3);
      *(uint2*)&lPw[pidx[n] + 1024] = pk1;
    }

    // PV + row-sum; V frags read once, feed both row-groups
    short8 pf00 = *(const short8*)&lPw[pra];
    short8 pf01 = *(const short8*)&lPw[prb];
    short8 pf10 = *(const short8*)&lPw[pra + 1024];
    short8 pf11 = *(const short8*)&lPw[prb + 1024];
    acc_l0 = mfma16(pf00, ones, acc_l0);
    acc_l0 = mfma16(pf01, ones, acc_l0);
    acc_l1 = mfma16(pf10, ones, acc_l1);
    acc_l1 = mfma16(pf11, ones, acc_l1);
    #pragma unroll
    for (int nd = 0; nd < 4; nd++){
      short8 vfa = *(const short8*)&lv[lo64 + nd * 1024 + ca0];
      short8 vfb = *(const short8*)&lv[lo64 + nd * 1024 + ca1];
      acc_o0[nd] = mfma16(pf00, vfa, acc_o0[nd]);
      acc_o0[nd] = mfma16(pf01, vfb, acc_o0[nd]);
      acc_o1[nd] = mfma16(pf10, vfa, acc_o1[nd]);
      acc_o1[nd] = mfma16(pf11, vfb, acc_o1[nd]);
    }

    // deferred rescale (PV above used old m_l -> consistent)
    bool ok = (m00 <= m_l0 + 8.f) && (m01 <= m_l1 + 8.f);
    if (!__all(ok)){
      float mn0 = fmaxf(m_l0, m00);
      float mn1 = fmaxf(m_l1, m01);
      float a00 = fexp2(m_l0 - mn0);
      float a01 = fexp2(m_l1 - mn1);
      m_l0 = mn0; m_l1 = mn1;
      #pragma unroll
      for (int r = 0; r < 4; r++){
        float ar0 = __shfl(a00, g * 4 + r, 64);
        float ar1 = __shfl(a01, g * 4 + r, 64);
        acc_l0[r] *= ar0;
        acc_l1[r] *= ar1;
        #pragma unroll
        for (int nd = 0; nd < 4; nd++){
          acc_o0[nd][r] *= ar0;
          acc_o1[nd][r] *= ar1;
        }
      }
    }

    cb ^= 8192;
    __syncthreads();
  }

  #pragma unroll
  for (int r = 0; r < 4; r++){
    float rl0 = 1.0f / acc_l0[r];
    float rl1 = 1.0f / acc_l1[r];
    #pragma unroll
    for (int nd = 0; nd < 4; nd++){
      int row0 = qRow0 + wv * 32 + g * 4 + r;
      int d    = colQ + (nd << 4) + lo;
      fb[(size_t)row0 * FD + d]        = f2bf(acc_o0[nd][r] * rl0);
      fb[(size_t)(row0 + 16) * FD + d] = f2bf(acc_o1[nd][r] * rl1);
    }
  }
}

extern "C" void kernel_launch(void* const* d_in, const int* in_sizes, int n_in,
                              void* d_out, int out_size, void* d_ws, size_t ws_size,
                              hipStream_t stream)
{
  const float* t1   = (const float*)d_in[0];
  const float* t2   = (const float*)d_in[1];
  const float* ln1g = (const float*)d_in[2];
  const float* ln1b = (const float*)d_in[3];
  const float* ln2g = (const float*)d_in[4];
  const float* ln2b = (const float*)d_in[5];
  const float* Wq   = (const float*)d_in[6];
  const float* bq   = (const float*)d_in[7];
  const float* Wk   = (const float*)d_in[8];
  const float* bk   = (const float*)d_in[9];
  const float* Wv   = (const float*)d_in[10];
  const float* bv   = (const float*)d_in[11];
  const float* Wfc  = (const float*)d_in[12];
  const float* bfc  = (const float*)d_in[13];
  const float* f1lg = (const float*)d_in[14];
  const float* f1lb = (const float*)d_in[15];
  const float* W11  = (const float*)d_in[16];
  const float* b11  = (const float*)d_in[17];
  const float* W12  = (const float*)d_in[18];
  const float* b12  = (const float*)d_in[19];
  const float* f2lg = (const float*)d_in[20];
  const float* f2lb = (const float*)d_in[21];
  const float* W21  = (const float*)d_in[22];
  const float* b21  = (const float*)d_in[23];
  const float* W22  = (const float*)d_in[24];
  const float* b22  = (const float*)d_in[25];

  char* ws = (char*)d_ws;
  const size_t MB = 1024 * 1024;
  u16* wt     = (u16*)ws;                  // 8 x [512,512] bf16 (transposed)
  u16* tln    = (u16*)(ws + 4 * MB);       // [16384,512]   (dead after QKV GEMM)
  u16* qkv    = (u16*)(ws + 20 * MB);      // [16384,1536]  (dead after attn)
  u16* fb     = (u16*)(ws + 68 * MB);      // [16384,512]
  float* bqkv = (float*)(ws + 84 * MB);    // [1536]
  u16* vtb    = (u16*)(ws + 85 * MB);      // V^T slabs [64][64][2048] (16 MB)
  u16* xln    = tln;                       // reuse after attn
  u16* hb     = qkv;                       // ff1 out: first 16MB of dead qkv
  u16* xb     = (u16*)(ws + 36 * MB);      // x as bf16: next 16MB of dead qkv
  float* out  = (float*)d_out;

  wconv_kernel<<<512, 256, 0, stream>>>(Wq, Wk, Wv, Wfc, W11, W12, W21, W22, wt);
  biascat_kernel<<<6, 256, 0, stream>>>(bq, bk, bv, bqkv);
  ln_kernel<false><<<4096, 256, 0, stream>>>(t1, t2, ln1g, ln1b, ln2g, ln2b, tln);
  gemm_bt<false, true, false, false, true><<<1536, 256, 0, stream>>>(
      tln, wt, wt, bqkv, bqkv, nullptr, nullptr, qkv, vtb, NTOT, QKVN, FD, NTOT);
  attn_kernel<<<512, 512, 0, stream>>>(qkv, vtb, fb);
  gemm_bt<false, true, true, false, false><<<512, 256, 0, stream>>>(
      fb, wt + 3 * 262144, wt + 3 * 262144, bfc, bfc, t1, t2, xb, nullptr, NTOT, FD, FD, NHALF);
  ln_kernel<true><<<4096, 256, 0, stream>>>(xb, xb + (size_t)NHALF * FD,
      f1lg, f1lb, f2lg, f2lb, xln);
  gemm_bt<true, true, false, false, false><<<512, 256, 0, stream>>>(
      xln, wt + 4 * 262144, wt + 6 * 262144, b11, b21, nullptr, nullptr, hb, nullptr, NTOT, FD, FD, NHALF);
  gemm_bt<false, false, true, true, false><<<512, 256, 0, stream>>>(
      hb, wt + 5 * 262144, wt + 7 * 262144, b12, b22, xb, xb + (size_t)NHALF * FD,
      out, nullptr, NTOT, FD, FD, NHALF);
}